// Round 12
// baseline (442.247 us; speedup 1.0000x reference)
//
#include <hip/hip_runtime.h>
#include <hip/hip_fp16.h>

#define N_NODES 100000
#define N_EDGES 1250000
#define HID 64
#define N_GRAPHS 512
#define OUT_CH 16

#define BK_NODES 64
#define NBUCKET ((N_NODES + BK_NODES - 1) / BK_NODES)  // 1563
#define NREP 8          // cursor replicas
#define SEG_CAP 192     // per-segment cap: mean 100, sigma 9.4 -> +9.8σ
#define BK_STRIDE (NREP * SEG_CAP)  // 1536 ints per bucket
#define TILE1 ((N_NODES + 63) / 64)  // 1563 blocks / buckets
#define TSTRIDE 68      // LDS T row stride (floats)
#define ZSTRIDE 72      // LDS Z row stride (h16): b128 reads 2-way (free)

typedef _Float16 h16;
typedef _Float16 half2_t __attribute__((ext_vector_type(2)));
typedef _Float16 f16x8 __attribute__((ext_vector_type(8)));
typedef float f32x4 __attribute__((ext_vector_type(4)));

__device__ __forceinline__ void acc2(unsigned int u, float& a0, float& a1) {
    half2_t h = __builtin_bit_cast(half2_t, u);
    a0 += (float)h[0];
    a1 += (float)h[1];
}

__device__ __forceinline__ unsigned pack2(float x, float y) {
    half2_t o;
    o[0] = (h16)x;
    o[1] = (h16)y;
    return __builtin_bit_cast(unsigned, o);
}

// ===========================================================================
// Partition edges into 64-node dst buckets, 8-way replicated cursors.
// Known floor (r5-r11): scattered-request pipe, ~66 µs. Unchanged.
// ===========================================================================
__global__ __launch_bounds__(256) void k_partition(const int* __restrict__ src,
                                                   const int* __restrict__ dst,
                                                   int* __restrict__ cnt,
                                                   int* __restrict__ buckets) {
    int rep = blockIdx.x & (NREP - 1);
    int i = blockIdx.x * blockDim.x + threadIdx.x;
    int stride = gridDim.x * blockDim.x;
    for (; i < N_EDGES; i += stride) {
        int s = src[i];
        int d = dst[i];
        int b = d >> 6;
        int pos = atomicAdd(&cnt[b * NREP + rep], 1);
        if (pos < SEG_CAP)
            buckets[(size_t)b * BK_STRIDE + rep * SEG_CAP + pos] = ((d & 63) << 17) | s;
    }
}

// ===========================================================================
// Merge the 8 segments of each bucket, sort by dstLocal in LDS, write back
// compacted + bucket-local rowptr [65]. Unchanged.
// ===========================================================================
__global__ __launch_bounds__(256) void k_bucket_sort(const int* __restrict__ cnt,
                                                     int* __restrict__ buckets,
                                                     int* __restrict__ rowptrL) {
    __shared__ int srt[BK_STRIDE];
    __shared__ int hist[BK_NODES];
    __shared__ int curs[BK_NODES];
    int b = blockIdx.x, t = threadIdx.x;
    int* gb = buckets + (size_t)b * BK_STRIDE;
    int c[NREP];
#pragma unroll
    for (int r = 0; r < NREP; ++r) {
        int x = cnt[b * NREP + r];
        c[r] = x < SEG_CAP ? x : SEG_CAP;
    }
    if (t < BK_NODES) hist[t] = 0;
    __syncthreads();
#pragma unroll
    for (int r = 0; r < NREP; ++r)
        for (int i = t; i < c[r]; i += 256)
            atomicAdd(&hist[gb[r * SEG_CAP + i] >> 17], 1);
    __syncthreads();
    if (t < 64) {
        int h = hist[t];
        int x = h;
        for (int off = 1; off < 64; off <<= 1) {
            int u = __shfl_up(x, off, 64);
            if (t >= off) x += u;
        }
        curs[t] = x - h;
        rowptrL[b * 65 + t] = x - h;
        if (t == 63) rowptrL[b * 65 + 64] = x;
    }
    __syncthreads();
#pragma unroll
    for (int r = 0; r < NREP; ++r)
        for (int i = t; i < c[r]; i += 256) {
            int rec = gb[r * SEG_CAP + i];
            int pos = atomicAdd(&curs[rec >> 17], 1);
            srt[pos] = rec;
        }
    __syncthreads();
    int n = 0;
#pragma unroll
    for (int r = 0; r < NREP; ++r) n += c[r];
    for (int i = t; i < n; i += 256) gb[i] = srt[i];
}

// ===========================================================================
// Weight prep (once per call): swizzle 7 64x64 fp32 matrices into fp16
// B-fragment order for mfma_f32_16x16x32_f16. Unchanged.
// ===========================================================================
__global__ __launch_bounds__(256) void k_wprep(const float* __restrict__ Wq0,
                                               const float* __restrict__ Wq1,
                                               const float* __restrict__ Wq2,
                                               const float* __restrict__ Wq3,
                                               const float* __restrict__ Wq4,
                                               const float* __restrict__ Wq5,
                                               const float* __restrict__ Wq6,
                                               h16* __restrict__ WF) {
    const float* Ws[7] = {Wq0, Wq1, Wq2, Wq3, Wq4, Wq5, Wq6};
    const float* W = Ws[blockIdx.x];
    h16* dstW = WF + (size_t)blockIdx.x * 4096;
    int t = threadIdx.x;
#pragma unroll
    for (int i = 0; i < 16; ++i) {
        int s = t + 256 * i;
        int k = s >> 6, col = s & 63;
        int kc = k >> 5, quad = (k >> 3) & 3, j = k & 7;
        int c = col >> 4, n = col & 15;
        dstW[((c * 2 + kc) * 4 + quad) * 128 + n * 8 + j] = (h16)W[s];
    }
}

// ===========================================================================
// FUSED GIN layer (r12): block = 64-node tile (= bucket).
// Phase 1: r11 aggregate (wave w -> its 16 local nodes, 8-edge unroll,
//   2ch/lane) writing Z into LDS fp16 (stride-72 rows).
// Phase 2: r10 MFMA MLP, A-frags via ds_read_b128 from sZ (2-way, free).
// Saves Z global write+read (25 MB/layer) + 1 launch per layer.
// ===========================================================================
__global__ __launch_bounds__(256) void k_layer(const int* __restrict__ rowptrL,
                                               const int* __restrict__ buckets,
                                               const h16* __restrict__ Hin,
                                               const h16* __restrict__ WaF,
                                               const float* __restrict__ Ba,
                                               const h16* __restrict__ WbF,
                                               const float* __restrict__ Bb,
                                               h16* __restrict__ Hout) {
    __shared__ h16 sZ[64 * ZSTRIDE];      // 9 KB
    __shared__ float sT[4 * 16 * TSTRIDE];  // 17.4 KB
    const unsigned* H2 = (const unsigned*)Hin;
    unsigned* sZ2 = (unsigned*)sZ;        // row stride 36 uints
    int t = threadIdx.x;
    int w = t >> 6, lane = t & 63;
    int half = lane >> 5, sub = lane & 31;
    int tile = blockIdx.x;
    const int* bk = buckets + (size_t)tile * BK_STRIDE;

    // ---- phase 1: aggregate into sZ ----
    for (int ii = 0; ii < 16; ++ii) {
        int local = w * 16 + ii;
        int i = tile * 64 + local;
        float a0 = 0.f, a1 = 0.f;
        if (i < N_NODES) {
            int start = rowptrL[tile * 65 + local];
            int end = rowptrL[tile * 65 + local + 1];
            if (half == 0) acc2(H2[(size_t)i * 32 + sub], a0, a1);
            int j = start;
            for (; j + 8 <= end; j += 8) {
                int s0 = bk[j + half] & 0x1FFFF;
                int s1 = bk[j + 2 + half] & 0x1FFFF;
                int s2 = bk[j + 4 + half] & 0x1FFFF;
                int s3 = bk[j + 6 + half] & 0x1FFFF;
                unsigned u0 = H2[(size_t)s0 * 32 + sub];
                unsigned u1 = H2[(size_t)s1 * 32 + sub];
                unsigned u2 = H2[(size_t)s2 * 32 + sub];
                unsigned u3 = H2[(size_t)s3 * 32 + sub];
                acc2(u0, a0, a1);
                acc2(u1, a0, a1);
                acc2(u2, a0, a1);
                acc2(u3, a0, a1);
            }
            if (j + 4 <= end) {
                int s0 = bk[j + half] & 0x1FFFF;
                int s1 = bk[j + 2 + half] & 0x1FFFF;
                unsigned u0 = H2[(size_t)s0 * 32 + sub];
                unsigned u1 = H2[(size_t)s1 * 32 + sub];
                acc2(u0, a0, a1);
                acc2(u1, a0, a1);
                j += 4;
            }
            if (j + 1 < end) {
                int s = bk[j + half] & 0x1FFFF;
                acc2(H2[(size_t)s * 32 + sub], a0, a1);
                j += 2;
            }
            if (j < end && half == 0) {
                int s = bk[j] & 0x1FFFF;
                acc2(H2[(size_t)s * 32 + sub], a0, a1);
            }
        }
        a0 += __shfl_xor(a0, 32, 64);
        a1 += __shfl_xor(a1, 32, 64);
        if (half == 0) sZ2[local * 36 + sub] = pack2(a0, a1);
    }
    __syncthreads();

    // ---- phase 2: MFMA MLP ----
    int n16 = lane & 15, quad = lane >> 4;
    float* T = sT + w * 16 * TSTRIDE;
    int rbase = tile * 64 + w * 16;

    f16x8 a0v = *(const f16x8*)&sZ[(w * 16 + n16) * ZSTRIDE + quad * 8];
    f16x8 a1v = *(const f16x8*)&sZ[(w * 16 + n16) * ZSTRIDE + 32 + quad * 8];

    f16x8 bwa[4][2], bwb[4][2];
#pragma unroll
    for (int c = 0; c < 4; ++c)
#pragma unroll
        for (int kc = 0; kc < 2; ++kc) {
            int f = ((c * 2 + kc) * 4 + quad) * 128 + n16 * 8;
            bwa[c][kc] = *(const f16x8*)(WaF + f);
            bwb[c][kc] = *(const f16x8*)(WbF + f);
        }

    f32x4 acc[4];
#pragma unroll
    for (int c = 0; c < 4; ++c) {
        float bv = Ba[c * 16 + n16];
        acc[c] = (f32x4){bv, bv, bv, bv};
        acc[c] = __builtin_amdgcn_mfma_f32_16x16x32_f16(a0v, bwa[c][0], acc[c], 0, 0, 0);
        acc[c] = __builtin_amdgcn_mfma_f32_16x16x32_f16(a1v, bwa[c][1], acc[c], 0, 0, 0);
    }

#pragma unroll
    for (int c = 0; c < 4; ++c)
#pragma unroll
        for (int r = 0; r < 4; ++r)
            T[(quad * 4 + r) * TSTRIDE + c * 16 + n16] = fmaxf(acc[c][r], 0.f);

    f16x8 ta[2];
#pragma unroll
    for (int kc = 0; kc < 2; ++kc) {
        float4 p = *(const float4*)&T[n16 * TSTRIDE + kc * 32 + quad * 8];
        float4 q = *(const float4*)&T[n16 * TSTRIDE + kc * 32 + quad * 8 + 4];
        f16x8 v;
        v[0] = (h16)p.x; v[1] = (h16)p.y; v[2] = (h16)p.z; v[3] = (h16)p.w;
        v[4] = (h16)q.x; v[5] = (h16)q.y; v[6] = (h16)q.z; v[7] = (h16)q.w;
        ta[kc] = v;
    }

#pragma unroll
    for (int c = 0; c < 4; ++c) {
        float bv = Bb[c * 16 + n16];
        acc[c] = (f32x4){bv, bv, bv, bv};
        acc[c] = __builtin_amdgcn_mfma_f32_16x16x32_f16(ta[0], bwb[c][0], acc[c], 0, 0, 0);
        acc[c] = __builtin_amdgcn_mfma_f32_16x16x32_f16(ta[1], bwb[c][1], acc[c], 0, 0, 0);
    }

#pragma unroll
    for (int c = 0; c < 4; ++c)
#pragma unroll
        for (int r = 0; r < 4; ++r)
            T[(quad * 4 + r) * TSTRIDE + c * 16 + n16] = fmaxf(acc[c][r], 0.f);
    {
        int rl = lane >> 2, seg = lane & 3;
        int row = rbase + rl;
        if (row < N_NODES) {
            const float* tr = &T[rl * TSTRIDE + seg * 16];
            f16x8 o0, o1;
#pragma unroll
            for (int i = 0; i < 8; ++i) {
                o0[i] = (h16)tr[i];
                o1[i] = (h16)tr[8 + i];
            }
            f16x8* dp = (f16x8*)(Hout + (size_t)row * HID + seg * 16);
            dp[0] = o0;
            dp[1] = o1;
        }
    }
}

// ===========================================================================
// MFMA input linear (r10, proven). Unchanged.
// ===========================================================================
__global__ __launch_bounds__(256) void k_lin(const h16* __restrict__ W0F,
                                             const float* __restrict__ B,
                                             const float* __restrict__ Xin,
                                             h16* __restrict__ Hout) {
    __shared__ float sT[4 * 16 * TSTRIDE];
    int t = threadIdx.x;
    int w = t >> 6, lane = t & 63;
    int n16 = lane & 15, quad = lane >> 4;
    float* T = sT + w * 16 * TSTRIDE;
    int rbase = blockIdx.x * 64 + w * 16;

    int arow = rbase + n16;
    int crow = arow < N_NODES ? arow : N_NODES - 1;
    f16x8 a[2];
#pragma unroll
    for (int kc = 0; kc < 2; ++kc) {
        const float4* xp = (const float4*)(Xin + (size_t)crow * HID + kc * 32 + quad * 8);
        float4 p = xp[0], q = xp[1];
        f16x8 v;
        v[0] = (h16)p.x; v[1] = (h16)p.y; v[2] = (h16)p.z; v[3] = (h16)p.w;
        v[4] = (h16)q.x; v[5] = (h16)q.y; v[6] = (h16)q.z; v[7] = (h16)q.w;
        a[kc] = v;
    }

    f32x4 acc[4];
#pragma unroll
    for (int c = 0; c < 4; ++c) {
        float bv = B[c * 16 + n16];
        acc[c] = (f32x4){bv, bv, bv, bv};
#pragma unroll
        for (int kc = 0; kc < 2; ++kc) {
            f16x8 bw = *(const f16x8*)(W0F + ((c * 2 + kc) * 4 + quad) * 128 + n16 * 8);
            acc[c] = __builtin_amdgcn_mfma_f32_16x16x32_f16(a[kc], bw, acc[c], 0, 0, 0);
        }
    }

#pragma unroll
    for (int c = 0; c < 4; ++c)
#pragma unroll
        for (int r = 0; r < 4; ++r)
            T[(quad * 4 + r) * TSTRIDE + c * 16 + n16] = fmaxf(acc[c][r], 0.f);
    {
        int rl = lane >> 2, seg = lane & 3;
        int row = rbase + rl;
        if (row < N_NODES) {
            const float* tr = &T[rl * TSTRIDE + seg * 16];
            f16x8 o0, o1;
#pragma unroll
            for (int i = 0; i < 8; ++i) {
                o0[i] = (h16)tr[i];
                o1[i] = (h16)tr[8 + i];
            }
            f16x8* dp = (f16x8*)(Hout + (size_t)row * HID + seg * 16);
            dp[0] = o0;
            dp[1] = o1;
        }
    }
}

// ===========================================================================
// Fused mean-pool + readout: one block per graph. Unchanged.
// ===========================================================================
__global__ __launch_bounds__(256) void k_poolfinal(const h16* __restrict__ H,
                                                   const int* __restrict__ batch,
                                                   const float* __restrict__ Wl,
                                                   const float* __restrict__ bl,
                                                   float* __restrict__ out) {
    __shared__ float sp[4 * HID];
    int g = blockIdx.x;
    int t = threadIdx.x;
    int lane = t & 63, w = t >> 6;
    int lo = 0, hi = N_NODES;
    while (lo < hi) { int m = (lo + hi) >> 1; if (batch[m] < g) lo = m + 1; else hi = m; }
    int start = lo;
    hi = N_NODES;
    while (lo < hi) { int m = (lo + hi) >> 1; if (batch[m] < g + 1) lo = m + 1; else hi = m; }
    int end = lo;
    float s = 0.f;
    for (int r = start + w; r < end; r += 4) s += (float)H[(size_t)r * HID + lane];
    sp[w * HID + lane] = s;
    __syncthreads();
    if (t < HID) {
        float tot = sp[t] + sp[HID + t] + sp[2 * HID + t] + sp[3 * HID + t];
        float c = (end > start) ? (float)(end - start) : 1.0f;
        sp[t] = tot / c;
    }
    __syncthreads();
    if (t < OUT_CH) {
        float acc = bl[t];
#pragma unroll
        for (int k = 0; k < HID; ++k) acc += sp[k] * Wl[k * OUT_CH + t];
        out[g * OUT_CH + t] = acc;
    }
}

extern "C" void kernel_launch(void* const* d_in, const int* in_sizes, int n_in,
                              void* d_out, int out_size, void* d_ws, size_t ws_size,
                              hipStream_t stream) {
    const float* x     = (const float*)d_in[0];
    const int*   edge  = (const int*)d_in[1];   // [2][N_EDGES] int32
    const int*   batch = (const int*)d_in[2];   // [N_NODES] int32 (sorted)
    const float* W0  = (const float*)d_in[3];
    const float* b0  = (const float*)d_in[4];
    const float* W1a = (const float*)d_in[5];
    const float* b1a = (const float*)d_in[6];
    const float* W1b = (const float*)d_in[7];
    const float* b1b = (const float*)d_in[8];
    const float* W2a = (const float*)d_in[9];
    const float* b2a = (const float*)d_in[10];
    const float* W2b = (const float*)d_in[11];
    const float* b2b = (const float*)d_in[12];
    const float* W3a = (const float*)d_in[13];
    const float* b3a = (const float*)d_in[14];
    const float* W3b = (const float*)d_in[15];
    const float* b3b = (const float*)d_in[16];
    const float* Wl  = (const float*)d_in[17];
    const float* bl  = (const float*)d_in[18];
    float* out = (float*)d_out;

    const int* src = edge;
    const int* dst = edge + N_EDGES;

    // Workspace: HA(fp16) | HB(fp16) | cnt | rowptrL | buckets | WF(fp16)
    h16* HA = (h16*)d_ws;
    h16* HB = HA + (size_t)N_NODES * HID;
    int* cnt     = (int*)(HB + (size_t)N_NODES * HID);
    int* rowptrL = cnt + NBUCKET * NREP;
    int* buckets = rowptrL + NBUCKET * 65;
    h16* WF      = (h16*)(buckets + (size_t)NBUCKET * BK_STRIDE);
    h16* W0F = WF;               // order: W0, W1a, W1b, W2a, W2b, W3a, W3b
    h16* W1aF = WF + 4096 * 1;
    h16* W1bF = WF + 4096 * 2;
    h16* W2aF = WF + 4096 * 3;
    h16* W2bF = WF + 4096 * 4;
    h16* W3aF = WF + 4096 * 5;
    h16* W3bF = WF + 4096 * 6;

    hipMemsetAsync(cnt, 0, NBUCKET * NREP * sizeof(int), stream);
    k_partition<<<4096, 256, 0, stream>>>(src, dst, cnt, buckets);
    k_bucket_sort<<<NBUCKET, 256, 0, stream>>>(cnt, buckets, rowptrL);
    k_wprep<<<7, 256, 0, stream>>>(W0, W1a, W1b, W2a, W2b, W3a, W3b, WF);

    k_lin<<<TILE1, 256, 0, stream>>>(W0F, b0, x, HA);

    k_layer<<<TILE1, 256, 0, stream>>>(rowptrL, buckets, HA, W1aF, b1a, W1bF, b1b, HB);
    k_layer<<<TILE1, 256, 0, stream>>>(rowptrL, buckets, HB, W2aF, b2a, W2bF, b2b, HA);
    k_layer<<<TILE1, 256, 0, stream>>>(rowptrL, buckets, HA, W3aF, b3a, W3bF, b3b, HB);

    k_poolfinal<<<N_GRAPHS, 256, 0, stream>>>(HB, batch, Wl, bl, out);
}

// Round 13
// 337.755 us; speedup vs baseline: 1.3094x; 1.3094x over previous
//
#include <hip/hip_runtime.h>
#include <hip/hip_fp16.h>

#define N_NODES 100000
#define N_EDGES 1250000
#define HID 64
#define N_GRAPHS 512
#define OUT_CH 16

#define BK_NODES 64
#define NBUCKET ((N_NODES + BK_NODES - 1) / BK_NODES)  // 1563
#define NREP 8          // cursor replicas
#define SEG_CAP 192     // per-segment cap: mean 100, sigma 9.4 -> +9.8σ
#define BK_STRIDE (NREP * SEG_CAP)  // 1536 ints per bucket
#define TILE1 ((N_NODES + 63) / 64)  // 1563 blocks
#define TSTRIDE 68      // LDS T row stride (floats)

typedef _Float16 h16;
typedef _Float16 half2_t __attribute__((ext_vector_type(2)));
typedef _Float16 f16x8 __attribute__((ext_vector_type(8)));
typedef float f32x4 __attribute__((ext_vector_type(4)));

__device__ __forceinline__ void acc4(uint2 u, float& a0, float& a1, float& a2, float& a3) {
    half2_t h0 = __builtin_bit_cast(half2_t, u.x);
    half2_t h1 = __builtin_bit_cast(half2_t, u.y);
    a0 += (float)h0[0];
    a1 += (float)h0[1];
    a2 += (float)h1[0];
    a3 += (float)h1[1];
}

__device__ __forceinline__ unsigned pack2(float x, float y) {
    half2_t o;
    o[0] = (h16)x;
    o[1] = (h16)y;
    return __builtin_bit_cast(unsigned, o);
}

// ===========================================================================
// Partition edges into 64-node dst buckets, 8-way replicated cursors.
// Known floor (r5-r12): scattered-request issue pipe, ~66 µs. Unchanged.
// ===========================================================================
__global__ __launch_bounds__(256) void k_partition(const int* __restrict__ src,
                                                   const int* __restrict__ dst,
                                                   int* __restrict__ cnt,
                                                   int* __restrict__ buckets) {
    int rep = blockIdx.x & (NREP - 1);
    int i = blockIdx.x * blockDim.x + threadIdx.x;
    int stride = gridDim.x * blockDim.x;
    for (; i < N_EDGES; i += stride) {
        int s = src[i];
        int d = dst[i];
        int b = d >> 6;
        int pos = atomicAdd(&cnt[b * NREP + rep], 1);
        if (pos < SEG_CAP)
            buckets[(size_t)b * BK_STRIDE + rep * SEG_CAP + pos] = ((d & 63) << 17) | s;
    }
}

// ===========================================================================
// Merge the 8 segments of each bucket, sort by dstLocal in LDS, write back
// compacted + bucket-local rowptr [65]. Unchanged.
// ===========================================================================
__global__ __launch_bounds__(256) void k_bucket_sort(const int* __restrict__ cnt,
                                                     int* __restrict__ buckets,
                                                     int* __restrict__ rowptrL) {
    __shared__ int srt[BK_STRIDE];
    __shared__ int hist[BK_NODES];
    __shared__ int curs[BK_NODES];
    int b = blockIdx.x, t = threadIdx.x;
    int* gb = buckets + (size_t)b * BK_STRIDE;
    int c[NREP];
#pragma unroll
    for (int r = 0; r < NREP; ++r) {
        int x = cnt[b * NREP + r];
        c[r] = x < SEG_CAP ? x : SEG_CAP;
    }
    if (t < BK_NODES) hist[t] = 0;
    __syncthreads();
#pragma unroll
    for (int r = 0; r < NREP; ++r)
        for (int i = t; i < c[r]; i += 256)
            atomicAdd(&hist[gb[r * SEG_CAP + i] >> 17], 1);
    __syncthreads();
    if (t < 64) {
        int h = hist[t];
        int x = h;
        for (int off = 1; off < 64; off <<= 1) {
            int u = __shfl_up(x, off, 64);
            if (t >= off) x += u;
        }
        curs[t] = x - h;
        rowptrL[b * 65 + t] = x - h;
        if (t == 63) rowptrL[b * 65 + 64] = x;
    }
    __syncthreads();
#pragma unroll
    for (int r = 0; r < NREP; ++r)
        for (int i = t; i < c[r]; i += 256) {
            int rec = gb[r * SEG_CAP + i];
            int pos = atomicAdd(&curs[rec >> 17], 1);
            srt[pos] = rec;
        }
    __syncthreads();
    int n = 0;
#pragma unroll
    for (int r = 0; r < NREP; ++r) n += c[r];
    for (int i = t; i < n; i += 256) gb[i] = srt[i];
}

// ===========================================================================
// Aggregate r13: QUARTER-wave per node. 16 lanes x 4ch (uint2) per row;
// a wave processes 4 consecutive nodes with independent 4-deep unrolls ->
// up to 16 in-flight gathers/wave (2x r11). Self-read + Z-store become one
// contiguous 512B wave transaction; no cross-lane combine needed.
// ===========================================================================
__global__ __launch_bounds__(256) void k_aggregate(const int* __restrict__ rowptrL,
                                                   const int* __restrict__ buckets,
                                                   const h16* __restrict__ H,
                                                   h16* __restrict__ Z) {
    const uint2* H4 = (const uint2*)H;  // 16 uint2 per row
    uint2* Z4 = (uint2*)Z;
    int lane = threadIdx.x & 63;
    int part = lane >> 4, sub = lane & 15;
    int gwave = (blockIdx.x * 256 + threadIdx.x) >> 6;
    int nw = (gridDim.x * 256) >> 6;
    for (int i0 = gwave * 4; i0 < N_NODES; i0 += nw * 4) {
        int i = i0 + part;
        bool valid = i < N_NODES;
        int iv = valid ? i : N_NODES - 1;
        int b = iv >> 6, local = iv & 63;
        int start = rowptrL[b * 65 + local];
        int end = valid ? rowptrL[b * 65 + local + 1] : start;
        const int* bk = buckets + (size_t)b * BK_STRIDE;
        float a0 = 0.f, a1 = 0.f, a2 = 0.f, a3 = 0.f;
        acc4(H4[(size_t)iv * 16 + sub], a0, a1, a2, a3);  // self term
        int j = start;
        for (; j + 4 <= end; j += 4) {
            int s0 = bk[j] & 0x1FFFF;
            int s1 = bk[j + 1] & 0x1FFFF;
            int s2 = bk[j + 2] & 0x1FFFF;
            int s3 = bk[j + 3] & 0x1FFFF;
            uint2 u0 = H4[(size_t)s0 * 16 + sub];
            uint2 u1 = H4[(size_t)s1 * 16 + sub];
            uint2 u2 = H4[(size_t)s2 * 16 + sub];
            uint2 u3 = H4[(size_t)s3 * 16 + sub];
            acc4(u0, a0, a1, a2, a3);
            acc4(u1, a0, a1, a2, a3);
            acc4(u2, a0, a1, a2, a3);
            acc4(u3, a0, a1, a2, a3);
        }
        if (j + 2 <= end) {
            int s0 = bk[j] & 0x1FFFF;
            int s1 = bk[j + 1] & 0x1FFFF;
            uint2 u0 = H4[(size_t)s0 * 16 + sub];
            uint2 u1 = H4[(size_t)s1 * 16 + sub];
            acc4(u0, a0, a1, a2, a3);
            acc4(u1, a0, a1, a2, a3);
            j += 2;
        }
        if (j < end) {
            int s = bk[j] & 0x1FFFF;
            acc4(H4[(size_t)s * 16 + sub], a0, a1, a2, a3);
        }
        if (valid) {
            uint2 o;
            o.x = pack2(a0, a1);
            o.y = pack2(a2, a3);
            Z4[(size_t)i * 16 + sub] = o;
        }
    }
}

// ===========================================================================
// Weight prep (once per call): swizzle 7 64x64 fp32 matrices into fp16
// B-fragment order for mfma_f32_16x16x32_f16. Unchanged.
// ===========================================================================
__global__ __launch_bounds__(256) void k_wprep(const float* __restrict__ Wq0,
                                               const float* __restrict__ Wq1,
                                               const float* __restrict__ Wq2,
                                               const float* __restrict__ Wq3,
                                               const float* __restrict__ Wq4,
                                               const float* __restrict__ Wq5,
                                               const float* __restrict__ Wq6,
                                               h16* __restrict__ WF) {
    const float* Ws[7] = {Wq0, Wq1, Wq2, Wq3, Wq4, Wq5, Wq6};
    const float* W = Ws[blockIdx.x];
    h16* dstW = WF + (size_t)blockIdx.x * 4096;
    int t = threadIdx.x;
#pragma unroll
    for (int i = 0; i < 16; ++i) {
        int s = t + 256 * i;
        int k = s >> 6, col = s & 63;
        int kc = k >> 5, quad = (k >> 3) & 3, j = k & 7;
        int c = col >> 4, n = col & 15;
        dstW[((c * 2 + kc) * 4 + quad) * 128 + n * 8 + j] = (h16)W[s];
    }
}

// ===========================================================================
// MFMA MLP (r10, proven): 64-row tile, wave = 16 rows x 64 cols, direct
// global A/B-frag loads, wave-private LDS transpose, zero __syncthreads.
// ===========================================================================
__global__ __launch_bounds__(256) void k_mlp(const h16* __restrict__ WaF,
                                             const float* __restrict__ Ba,
                                             const h16* __restrict__ WbF,
                                             const float* __restrict__ Bb,
                                             const h16* __restrict__ Zin,
                                             h16* __restrict__ Hout) {
    __shared__ float sT[4 * 16 * TSTRIDE];
    int t = threadIdx.x;
    int w = t >> 6, lane = t & 63;
    int n16 = lane & 15, quad = lane >> 4;
    float* T = sT + w * 16 * TSTRIDE;
    int rbase = blockIdx.x * 64 + w * 16;

    int arow = rbase + n16;
    int crow = arow < N_NODES ? arow : N_NODES - 1;
    const f16x8* zp = (const f16x8*)(Zin + (size_t)crow * HID + quad * 8);
    f16x8 a0 = zp[0];
    f16x8 a1 = zp[4];

    f16x8 bwa[4][2], bwb[4][2];
#pragma unroll
    for (int c = 0; c < 4; ++c)
#pragma unroll
        for (int kc = 0; kc < 2; ++kc) {
            int f = ((c * 2 + kc) * 4 + quad) * 128 + n16 * 8;
            bwa[c][kc] = *(const f16x8*)(WaF + f);
            bwb[c][kc] = *(const f16x8*)(WbF + f);
        }

    f32x4 acc[4];
#pragma unroll
    for (int c = 0; c < 4; ++c) {
        float bv = Ba[c * 16 + n16];
        acc[c] = (f32x4){bv, bv, bv, bv};
        acc[c] = __builtin_amdgcn_mfma_f32_16x16x32_f16(a0, bwa[c][0], acc[c], 0, 0, 0);
        acc[c] = __builtin_amdgcn_mfma_f32_16x16x32_f16(a1, bwa[c][1], acc[c], 0, 0, 0);
    }

#pragma unroll
    for (int c = 0; c < 4; ++c)
#pragma unroll
        for (int r = 0; r < 4; ++r)
            T[(quad * 4 + r) * TSTRIDE + c * 16 + n16] = fmaxf(acc[c][r], 0.f);

    f16x8 ta[2];
#pragma unroll
    for (int kc = 0; kc < 2; ++kc) {
        float4 p = *(const float4*)&T[n16 * TSTRIDE + kc * 32 + quad * 8];
        float4 q = *(const float4*)&T[n16 * TSTRIDE + kc * 32 + quad * 8 + 4];
        f16x8 v;
        v[0] = (h16)p.x; v[1] = (h16)p.y; v[2] = (h16)p.z; v[3] = (h16)p.w;
        v[4] = (h16)q.x; v[5] = (h16)q.y; v[6] = (h16)q.z; v[7] = (h16)q.w;
        ta[kc] = v;
    }

#pragma unroll
    for (int c = 0; c < 4; ++c) {
        float bv = Bb[c * 16 + n16];
        acc[c] = (f32x4){bv, bv, bv, bv};
        acc[c] = __builtin_amdgcn_mfma_f32_16x16x32_f16(ta[0], bwb[c][0], acc[c], 0, 0, 0);
        acc[c] = __builtin_amdgcn_mfma_f32_16x16x32_f16(ta[1], bwb[c][1], acc[c], 0, 0, 0);
    }

#pragma unroll
    for (int c = 0; c < 4; ++c)
#pragma unroll
        for (int r = 0; r < 4; ++r)
            T[(quad * 4 + r) * TSTRIDE + c * 16 + n16] = fmaxf(acc[c][r], 0.f);
    {
        int rl = lane >> 2, seg = lane & 3;
        int row = rbase + rl;
        if (row < N_NODES) {
            const float* tr = &T[rl * TSTRIDE + seg * 16];
            f16x8 o0, o1;
#pragma unroll
            for (int i = 0; i < 8; ++i) {
                o0[i] = (h16)tr[i];
                o1[i] = (h16)tr[8 + i];
            }
            f16x8* dp = (f16x8*)(Hout + (size_t)row * HID + seg * 16);
            dp[0] = o0;
            dp[1] = o1;
        }
    }
}

// ===========================================================================
// MFMA input linear (r10, proven). Unchanged.
// ===========================================================================
__global__ __launch_bounds__(256) void k_lin(const h16* __restrict__ W0F,
                                             const float* __restrict__ B,
                                             const float* __restrict__ Xin,
                                             h16* __restrict__ Hout) {
    __shared__ float sT[4 * 16 * TSTRIDE];
    int t = threadIdx.x;
    int w = t >> 6, lane = t & 63;
    int n16 = lane & 15, quad = lane >> 4;
    float* T = sT + w * 16 * TSTRIDE;
    int rbase = blockIdx.x * 64 + w * 16;

    int arow = rbase + n16;
    int crow = arow < N_NODES ? arow : N_NODES - 1;
    f16x8 a[2];
#pragma unroll
    for (int kc = 0; kc < 2; ++kc) {
        const float4* xp = (const float4*)(Xin + (size_t)crow * HID + kc * 32 + quad * 8);
        float4 p = xp[0], q = xp[1];
        f16x8 v;
        v[0] = (h16)p.x; v[1] = (h16)p.y; v[2] = (h16)p.z; v[3] = (h16)p.w;
        v[4] = (h16)q.x; v[5] = (h16)q.y; v[6] = (h16)q.z; v[7] = (h16)q.w;
        a[kc] = v;
    }

    f32x4 acc[4];
#pragma unroll
    for (int c = 0; c < 4; ++c) {
        float bv = B[c * 16 + n16];
        acc[c] = (f32x4){bv, bv, bv, bv};
#pragma unroll
        for (int kc = 0; kc < 2; ++kc) {
            f16x8 bw = *(const f16x8*)(W0F + ((c * 2 + kc) * 4 + quad) * 128 + n16 * 8);
            acc[c] = __builtin_amdgcn_mfma_f32_16x16x32_f16(a[kc], bw, acc[c], 0, 0, 0);
        }
    }

#pragma unroll
    for (int c = 0; c < 4; ++c)
#pragma unroll
        for (int r = 0; r < 4; ++r)
            T[(quad * 4 + r) * TSTRIDE + c * 16 + n16] = fmaxf(acc[c][r], 0.f);
    {
        int rl = lane >> 2, seg = lane & 3;
        int row = rbase + rl;
        if (row < N_NODES) {
            const float* tr = &T[rl * TSTRIDE + seg * 16];
            f16x8 o0, o1;
#pragma unroll
            for (int i = 0; i < 8; ++i) {
                o0[i] = (h16)tr[i];
                o1[i] = (h16)tr[8 + i];
            }
            f16x8* dp = (f16x8*)(Hout + (size_t)row * HID + seg * 16);
            dp[0] = o0;
            dp[1] = o1;
        }
    }
}

// ===========================================================================
// Fused mean-pool + readout: one block per graph. Unchanged.
// ===========================================================================
__global__ __launch_bounds__(256) void k_poolfinal(const h16* __restrict__ H,
                                                   const int* __restrict__ batch,
                                                   const float* __restrict__ Wl,
                                                   const float* __restrict__ bl,
                                                   float* __restrict__ out) {
    __shared__ float sp[4 * HID];
    int g = blockIdx.x;
    int t = threadIdx.x;
    int lane = t & 63, w = t >> 6;
    int lo = 0, hi = N_NODES;
    while (lo < hi) { int m = (lo + hi) >> 1; if (batch[m] < g) lo = m + 1; else hi = m; }
    int start = lo;
    hi = N_NODES;
    while (lo < hi) { int m = (lo + hi) >> 1; if (batch[m] < g + 1) lo = m + 1; else hi = m; }
    int end = lo;
    float s = 0.f;
    for (int r = start + w; r < end; r += 4) s += (float)H[(size_t)r * HID + lane];
    sp[w * HID + lane] = s;
    __syncthreads();
    if (t < HID) {
        float tot = sp[t] + sp[HID + t] + sp[2 * HID + t] + sp[3 * HID + t];
        float c = (end > start) ? (float)(end - start) : 1.0f;
        sp[t] = tot / c;
    }
    __syncthreads();
    if (t < OUT_CH) {
        float acc = bl[t];
#pragma unroll
        for (int k = 0; k < HID; ++k) acc += sp[k] * Wl[k * OUT_CH + t];
        out[g * OUT_CH + t] = acc;
    }
}

extern "C" void kernel_launch(void* const* d_in, const int* in_sizes, int n_in,
                              void* d_out, int out_size, void* d_ws, size_t ws_size,
                              hipStream_t stream) {
    const float* x     = (const float*)d_in[0];
    const int*   edge  = (const int*)d_in[1];   // [2][N_EDGES] int32
    const int*   batch = (const int*)d_in[2];   // [N_NODES] int32 (sorted)
    const float* W0  = (const float*)d_in[3];
    const float* b0  = (const float*)d_in[4];
    const float* W1a = (const float*)d_in[5];
    const float* b1a = (const float*)d_in[6];
    const float* W1b = (const float*)d_in[7];
    const float* b1b = (const float*)d_in[8];
    const float* W2a = (const float*)d_in[9];
    const float* b2a = (const float*)d_in[10];
    const float* W2b = (const float*)d_in[11];
    const float* b2b = (const float*)d_in[12];
    const float* W3a = (const float*)d_in[13];
    const float* b3a = (const float*)d_in[14];
    const float* W3b = (const float*)d_in[15];
    const float* b3b = (const float*)d_in[16];
    const float* Wl  = (const float*)d_in[17];
    const float* bl  = (const float*)d_in[18];
    float* out = (float*)d_out;

    const int* src = edge;
    const int* dst = edge + N_EDGES;

    // Workspace: HA(fp16) | Z(fp16) | cnt | rowptrL | buckets | WF(fp16)
    h16* HA = (h16*)d_ws;
    h16* Z  = HA + (size_t)N_NODES * HID;
    int* cnt     = (int*)(Z + (size_t)N_NODES * HID);
    int* rowptrL = cnt + NBUCKET * NREP;
    int* buckets = rowptrL + NBUCKET * 65;
    h16* WF      = (h16*)(buckets + (size_t)NBUCKET * BK_STRIDE);
    h16* W0F = WF;               // order: W0, W1a, W1b, W2a, W2b, W3a, W3b
    h16* W1aF = WF + 4096 * 1;
    h16* W1bF = WF + 4096 * 2;
    h16* W2aF = WF + 4096 * 3;
    h16* W2bF = WF + 4096 * 4;
    h16* W3aF = WF + 4096 * 5;
    h16* W3bF = WF + 4096 * 6;

    hipMemsetAsync(cnt, 0, NBUCKET * NREP * sizeof(int), stream);
    k_partition<<<4096, 256, 0, stream>>>(src, dst, cnt, buckets);
    k_bucket_sort<<<NBUCKET, 256, 0, stream>>>(cnt, buckets, rowptrL);
    k_wprep<<<7, 256, 0, stream>>>(W0, W1a, W1b, W2a, W2b, W3a, W3b, WF);

    k_lin<<<TILE1, 256, 0, stream>>>(W0F, b0, x, HA);

    k_aggregate<<<6250, 256, 0, stream>>>(rowptrL, buckets, HA, Z);
    k_mlp<<<TILE1, 256, 0, stream>>>(W1aF, b1a, W1bF, b1b, Z, HA);

    k_aggregate<<<6250, 256, 0, stream>>>(rowptrL, buckets, HA, Z);
    k_mlp<<<TILE1, 256, 0, stream>>>(W2aF, b2a, W2bF, b2b, Z, HA);

    k_aggregate<<<6250, 256, 0, stream>>>(rowptrL, buckets, HA, Z);
    k_mlp<<<TILE1, 256, 0, stream>>>(W3aF, b3a, W3bF, b3b, Z, HA);

    k_poolfinal<<<N_GRAPHS, 256, 0, stream>>>(HA, batch, Wl, bl, out);
}

// Round 14
// 330.675 us; speedup vs baseline: 1.3374x; 1.0214x over previous
//
#include <hip/hip_runtime.h>
#include <hip/hip_fp16.h>

#define N_NODES 100000
#define N_EDGES 1250000
#define HID 64
#define N_GRAPHS 512
#define OUT_CH 16

#define BK_NODES 64
#define NBUCKET ((N_NODES + BK_NODES - 1) / BK_NODES)  // 1563
#define NREP 8          // cursor replicas
#define SEG_CAP 192     // per-segment cap: mean 100, sigma 9.4 -> +9.8σ
#define BK_STRIDE (NREP * SEG_CAP)  // 1536 ints per bucket
#define TILE1 ((N_NODES + 63) / 64)  // 1563 blocks
#define TSTRIDE 68      // LDS T row stride (floats)

typedef _Float16 h16;
typedef _Float16 half2_t __attribute__((ext_vector_type(2)));
typedef _Float16 f16x8 __attribute__((ext_vector_type(8)));
typedef float f32x4 __attribute__((ext_vector_type(4)));

__device__ __forceinline__ void acc4(uint2 u, float& a0, float& a1, float& a2, float& a3) {
    half2_t h0 = __builtin_bit_cast(half2_t, u.x);
    half2_t h1 = __builtin_bit_cast(half2_t, u.y);
    a0 += (float)h0[0];
    a1 += (float)h0[1];
    a2 += (float)h1[0];
    a3 += (float)h1[1];
}

__device__ __forceinline__ unsigned pack2(float x, float y) {
    half2_t o;
    o[0] = (h16)x;
    o[1] = (h16)y;
    return __builtin_bit_cast(unsigned, o);
}

// ===========================================================================
// Partition edges into 64-node dst buckets, 8-way replicated cursors.
// r14: single-pass (1 edge/thread, no loop) to maximize in-flight scatters.
// Known floor (r5-r13): ~16 cyc/scattered-request issue pipe.
// ===========================================================================
__global__ __launch_bounds__(256) void k_partition(const int* __restrict__ src,
                                                   const int* __restrict__ dst,
                                                   int* __restrict__ cnt,
                                                   int* __restrict__ buckets) {
    int i = blockIdx.x * 256 + threadIdx.x;
    if (i >= N_EDGES) return;
    int rep = blockIdx.x & (NREP - 1);
    int s = src[i];
    int d = dst[i];
    int b = d >> 6;
    int pos = atomicAdd(&cnt[b * NREP + rep], 1);
    if (pos < SEG_CAP)
        buckets[(size_t)b * BK_STRIDE + rep * SEG_CAP + pos] = ((d & 63) << 17) | s;
}

// ===========================================================================
// Merge the 8 segments of each bucket, sort by dstLocal in LDS, write back
// compacted + bucket-local rowptr [65]. Unchanged.
// ===========================================================================
__global__ __launch_bounds__(256) void k_bucket_sort(const int* __restrict__ cnt,
                                                     int* __restrict__ buckets,
                                                     int* __restrict__ rowptrL) {
    __shared__ int srt[BK_STRIDE];
    __shared__ int hist[BK_NODES];
    __shared__ int curs[BK_NODES];
    int b = blockIdx.x, t = threadIdx.x;
    int* gb = buckets + (size_t)b * BK_STRIDE;
    int c[NREP];
#pragma unroll
    for (int r = 0; r < NREP; ++r) {
        int x = cnt[b * NREP + r];
        c[r] = x < SEG_CAP ? x : SEG_CAP;
    }
    if (t < BK_NODES) hist[t] = 0;
    __syncthreads();
#pragma unroll
    for (int r = 0; r < NREP; ++r)
        for (int i = t; i < c[r]; i += 256)
            atomicAdd(&hist[gb[r * SEG_CAP + i] >> 17], 1);
    __syncthreads();
    if (t < 64) {
        int h = hist[t];
        int x = h;
        for (int off = 1; off < 64; off <<= 1) {
            int u = __shfl_up(x, off, 64);
            if (t >= off) x += u;
        }
        curs[t] = x - h;
        rowptrL[b * 65 + t] = x - h;
        if (t == 63) rowptrL[b * 65 + 64] = x;
    }
    __syncthreads();
#pragma unroll
    for (int r = 0; r < NREP; ++r)
        for (int i = t; i < c[r]; i += 256) {
            int rec = gb[r * SEG_CAP + i];
            int pos = atomicAdd(&curs[rec >> 17], 1);
            srt[pos] = rec;
        }
    __syncthreads();
    int n = 0;
#pragma unroll
    for (int r = 0; r < NREP; ++r) n += c[r];
    for (int i = t; i < n; i += 256) gb[i] = srt[i];
}

// ===========================================================================
// Aggregate r14: quarter-wave per node (r13) + 8-deep unroll (r11 lesson)
// -> up to 32 in-flight line-pairs per wave. Ceiling probe: flat = random-
// line service floor reached.
// ===========================================================================
__global__ __launch_bounds__(256) void k_aggregate(const int* __restrict__ rowptrL,
                                                   const int* __restrict__ buckets,
                                                   const h16* __restrict__ H,
                                                   h16* __restrict__ Z) {
    const uint2* H4 = (const uint2*)H;  // 16 uint2 per row
    uint2* Z4 = (uint2*)Z;
    int lane = threadIdx.x & 63;
    int part = lane >> 4, sub = lane & 15;
    int gwave = (blockIdx.x * 256 + threadIdx.x) >> 6;
    int nw = (gridDim.x * 256) >> 6;
    for (int i0 = gwave * 4; i0 < N_NODES; i0 += nw * 4) {
        int i = i0 + part;
        bool valid = i < N_NODES;
        int iv = valid ? i : N_NODES - 1;
        int b = iv >> 6, local = iv & 63;
        int start = rowptrL[b * 65 + local];
        int end = valid ? rowptrL[b * 65 + local + 1] : start;
        const int* bk = buckets + (size_t)b * BK_STRIDE;
        float a0 = 0.f, a1 = 0.f, a2 = 0.f, a3 = 0.f;
        acc4(H4[(size_t)iv * 16 + sub], a0, a1, a2, a3);  // self term
        int j = start;
        for (; j + 8 <= end; j += 8) {
            int s0 = bk[j] & 0x1FFFF;
            int s1 = bk[j + 1] & 0x1FFFF;
            int s2 = bk[j + 2] & 0x1FFFF;
            int s3 = bk[j + 3] & 0x1FFFF;
            int s4 = bk[j + 4] & 0x1FFFF;
            int s5 = bk[j + 5] & 0x1FFFF;
            int s6 = bk[j + 6] & 0x1FFFF;
            int s7 = bk[j + 7] & 0x1FFFF;
            uint2 u0 = H4[(size_t)s0 * 16 + sub];
            uint2 u1 = H4[(size_t)s1 * 16 + sub];
            uint2 u2 = H4[(size_t)s2 * 16 + sub];
            uint2 u3 = H4[(size_t)s3 * 16 + sub];
            uint2 u4 = H4[(size_t)s4 * 16 + sub];
            uint2 u5 = H4[(size_t)s5 * 16 + sub];
            uint2 u6 = H4[(size_t)s6 * 16 + sub];
            uint2 u7 = H4[(size_t)s7 * 16 + sub];
            acc4(u0, a0, a1, a2, a3);
            acc4(u1, a0, a1, a2, a3);
            acc4(u2, a0, a1, a2, a3);
            acc4(u3, a0, a1, a2, a3);
            acc4(u4, a0, a1, a2, a3);
            acc4(u5, a0, a1, a2, a3);
            acc4(u6, a0, a1, a2, a3);
            acc4(u7, a0, a1, a2, a3);
        }
        if (j + 4 <= end) {
            int s0 = bk[j] & 0x1FFFF;
            int s1 = bk[j + 1] & 0x1FFFF;
            int s2 = bk[j + 2] & 0x1FFFF;
            int s3 = bk[j + 3] & 0x1FFFF;
            uint2 u0 = H4[(size_t)s0 * 16 + sub];
            uint2 u1 = H4[(size_t)s1 * 16 + sub];
            uint2 u2 = H4[(size_t)s2 * 16 + sub];
            uint2 u3 = H4[(size_t)s3 * 16 + sub];
            acc4(u0, a0, a1, a2, a3);
            acc4(u1, a0, a1, a2, a3);
            acc4(u2, a0, a1, a2, a3);
            acc4(u3, a0, a1, a2, a3);
            j += 4;
        }
        if (j + 2 <= end) {
            int s0 = bk[j] & 0x1FFFF;
            int s1 = bk[j + 1] & 0x1FFFF;
            uint2 u0 = H4[(size_t)s0 * 16 + sub];
            uint2 u1 = H4[(size_t)s1 * 16 + sub];
            acc4(u0, a0, a1, a2, a3);
            acc4(u1, a0, a1, a2, a3);
            j += 2;
        }
        if (j < end) {
            int s = bk[j] & 0x1FFFF;
            acc4(H4[(size_t)s * 16 + sub], a0, a1, a2, a3);
        }
        if (valid) {
            uint2 o;
            o.x = pack2(a0, a1);
            o.y = pack2(a2, a3);
            Z4[(size_t)i * 16 + sub] = o;
        }
    }
}

// ===========================================================================
// Weight prep (once per call): swizzle 7 64x64 fp32 matrices into fp16
// B-fragment order for mfma_f32_16x16x32_f16. Unchanged.
// ===========================================================================
__global__ __launch_bounds__(256) void k_wprep(const float* __restrict__ Wq0,
                                               const float* __restrict__ Wq1,
                                               const float* __restrict__ Wq2,
                                               const float* __restrict__ Wq3,
                                               const float* __restrict__ Wq4,
                                               const float* __restrict__ Wq5,
                                               const float* __restrict__ Wq6,
                                               h16* __restrict__ WF) {
    const float* Ws[7] = {Wq0, Wq1, Wq2, Wq3, Wq4, Wq5, Wq6};
    const float* W = Ws[blockIdx.x];
    h16* dstW = WF + (size_t)blockIdx.x * 4096;
    int t = threadIdx.x;
#pragma unroll
    for (int i = 0; i < 16; ++i) {
        int s = t + 256 * i;
        int k = s >> 6, col = s & 63;
        int kc = k >> 5, quad = (k >> 3) & 3, j = k & 7;
        int c = col >> 4, n = col & 15;
        dstW[((c * 2 + kc) * 4 + quad) * 128 + n * 8 + j] = (h16)W[s];
    }
}

// ===========================================================================
// MFMA MLP (r10, proven): 64-row tile, wave = 16 rows x 64 cols, direct
// global A/B-frag loads, wave-private LDS transpose, zero __syncthreads.
// ===========================================================================
__global__ __launch_bounds__(256) void k_mlp(const h16* __restrict__ WaF,
                                             const float* __restrict__ Ba,
                                             const h16* __restrict__ WbF,
                                             const float* __restrict__ Bb,
                                             const h16* __restrict__ Zin,
                                             h16* __restrict__ Hout) {
    __shared__ float sT[4 * 16 * TSTRIDE];
    int t = threadIdx.x;
    int w = t >> 6, lane = t & 63;
    int n16 = lane & 15, quad = lane >> 4;
    float* T = sT + w * 16 * TSTRIDE;
    int rbase = blockIdx.x * 64 + w * 16;

    int arow = rbase + n16;
    int crow = arow < N_NODES ? arow : N_NODES - 1;
    const f16x8* zp = (const f16x8*)(Zin + (size_t)crow * HID + quad * 8);
    f16x8 a0 = zp[0];
    f16x8 a1 = zp[4];

    f16x8 bwa[4][2], bwb[4][2];
#pragma unroll
    for (int c = 0; c < 4; ++c)
#pragma unroll
        for (int kc = 0; kc < 2; ++kc) {
            int f = ((c * 2 + kc) * 4 + quad) * 128 + n16 * 8;
            bwa[c][kc] = *(const f16x8*)(WaF + f);
            bwb[c][kc] = *(const f16x8*)(WbF + f);
        }

    f32x4 acc[4];
#pragma unroll
    for (int c = 0; c < 4; ++c) {
        float bv = Ba[c * 16 + n16];
        acc[c] = (f32x4){bv, bv, bv, bv};
        acc[c] = __builtin_amdgcn_mfma_f32_16x16x32_f16(a0, bwa[c][0], acc[c], 0, 0, 0);
        acc[c] = __builtin_amdgcn_mfma_f32_16x16x32_f16(a1, bwa[c][1], acc[c], 0, 0, 0);
    }

#pragma unroll
    for (int c = 0; c < 4; ++c)
#pragma unroll
        for (int r = 0; r < 4; ++r)
            T[(quad * 4 + r) * TSTRIDE + c * 16 + n16] = fmaxf(acc[c][r], 0.f);

    f16x8 ta[2];
#pragma unroll
    for (int kc = 0; kc < 2; ++kc) {
        float4 p = *(const float4*)&T[n16 * TSTRIDE + kc * 32 + quad * 8];
        float4 q = *(const float4*)&T[n16 * TSTRIDE + kc * 32 + quad * 8 + 4];
        f16x8 v;
        v[0] = (h16)p.x; v[1] = (h16)p.y; v[2] = (h16)p.z; v[3] = (h16)p.w;
        v[4] = (h16)q.x; v[5] = (h16)q.y; v[6] = (h16)q.z; v[7] = (h16)q.w;
        ta[kc] = v;
    }

#pragma unroll
    for (int c = 0; c < 4; ++c) {
        float bv = Bb[c * 16 + n16];
        acc[c] = (f32x4){bv, bv, bv, bv};
        acc[c] = __builtin_amdgcn_mfma_f32_16x16x32_f16(ta[0], bwb[c][0], acc[c], 0, 0, 0);
        acc[c] = __builtin_amdgcn_mfma_f32_16x16x32_f16(ta[1], bwb[c][1], acc[c], 0, 0, 0);
    }

#pragma unroll
    for (int c = 0; c < 4; ++c)
#pragma unroll
        for (int r = 0; r < 4; ++r)
            T[(quad * 4 + r) * TSTRIDE + c * 16 + n16] = fmaxf(acc[c][r], 0.f);
    {
        int rl = lane >> 2, seg = lane & 3;
        int row = rbase + rl;
        if (row < N_NODES) {
            const float* tr = &T[rl * TSTRIDE + seg * 16];
            f16x8 o0, o1;
#pragma unroll
            for (int i = 0; i < 8; ++i) {
                o0[i] = (h16)tr[i];
                o1[i] = (h16)tr[8 + i];
            }
            f16x8* dp = (f16x8*)(Hout + (size_t)row * HID + seg * 16);
            dp[0] = o0;
            dp[1] = o1;
        }
    }
}

// ===========================================================================
// MFMA input linear (r10, proven). Unchanged.
// ===========================================================================
__global__ __launch_bounds__(256) void k_lin(const h16* __restrict__ W0F,
                                             const float* __restrict__ B,
                                             const float* __restrict__ Xin,
                                             h16* __restrict__ Hout) {
    __shared__ float sT[4 * 16 * TSTRIDE];
    int t = threadIdx.x;
    int w = t >> 6, lane = t & 63;
    int n16 = lane & 15, quad = lane >> 4;
    float* T = sT + w * 16 * TSTRIDE;
    int rbase = blockIdx.x * 64 + w * 16;

    int arow = rbase + n16;
    int crow = arow < N_NODES ? arow : N_NODES - 1;
    f16x8 a[2];
#pragma unroll
    for (int kc = 0; kc < 2; ++kc) {
        const float4* xp = (const float4*)(Xin + (size_t)crow * HID + kc * 32 + quad * 8);
        float4 p = xp[0], q = xp[1];
        f16x8 v;
        v[0] = (h16)p.x; v[1] = (h16)p.y; v[2] = (h16)p.z; v[3] = (h16)p.w;
        v[4] = (h16)q.x; v[5] = (h16)q.y; v[6] = (h16)q.z; v[7] = (h16)q.w;
        a[kc] = v;
    }

    f32x4 acc[4];
#pragma unroll
    for (int c = 0; c < 4; ++c) {
        float bv = B[c * 16 + n16];
        acc[c] = (f32x4){bv, bv, bv, bv};
#pragma unroll
        for (int kc = 0; kc < 2; ++kc) {
            f16x8 bw = *(const f16x8*)(W0F + ((c * 2 + kc) * 4 + quad) * 128 + n16 * 8);
            acc[c] = __builtin_amdgcn_mfma_f32_16x16x32_f16(a[kc], bw, acc[c], 0, 0, 0);
        }
    }

#pragma unroll
    for (int c = 0; c < 4; ++c)
#pragma unroll
        for (int r = 0; r < 4; ++r)
            T[(quad * 4 + r) * TSTRIDE + c * 16 + n16] = fmaxf(acc[c][r], 0.f);
    {
        int rl = lane >> 2, seg = lane & 3;
        int row = rbase + rl;
        if (row < N_NODES) {
            const float* tr = &T[rl * TSTRIDE + seg * 16];
            f16x8 o0, o1;
#pragma unroll
            for (int i = 0; i < 8; ++i) {
                o0[i] = (h16)tr[i];
                o1[i] = (h16)tr[8 + i];
            }
            f16x8* dp = (f16x8*)(Hout + (size_t)row * HID + seg * 16);
            dp[0] = o0;
            dp[1] = o1;
        }
    }
}

// ===========================================================================
// Fused mean-pool + readout: one block per graph. Unchanged.
// ===========================================================================
__global__ __launch_bounds__(256) void k_poolfinal(const h16* __restrict__ H,
                                                   const int* __restrict__ batch,
                                                   const float* __restrict__ Wl,
                                                   const float* __restrict__ bl,
                                                   float* __restrict__ out) {
    __shared__ float sp[4 * HID];
    int g = blockIdx.x;
    int t = threadIdx.x;
    int lane = t & 63, w = t >> 6;
    int lo = 0, hi = N_NODES;
    while (lo < hi) { int m = (lo + hi) >> 1; if (batch[m] < g) lo = m + 1; else hi = m; }
    int start = lo;
    hi = N_NODES;
    while (lo < hi) { int m = (lo + hi) >> 1; if (batch[m] < g + 1) lo = m + 1; else hi = m; }
    int end = lo;
    float s = 0.f;
    for (int r = start + w; r < end; r += 4) s += (float)H[(size_t)r * HID + lane];
    sp[w * HID + lane] = s;
    __syncthreads();
    if (t < HID) {
        float tot = sp[t] + sp[HID + t] + sp[2 * HID + t] + sp[3 * HID + t];
        float c = (end > start) ? (float)(end - start) : 1.0f;
        sp[t] = tot / c;
    }
    __syncthreads();
    if (t < OUT_CH) {
        float acc = bl[t];
#pragma unroll
        for (int k = 0; k < HID; ++k) acc += sp[k] * Wl[k * OUT_CH + t];
        out[g * OUT_CH + t] = acc;
    }
}

extern "C" void kernel_launch(void* const* d_in, const int* in_sizes, int n_in,
                              void* d_out, int out_size, void* d_ws, size_t ws_size,
                              hipStream_t stream) {
    const float* x     = (const float*)d_in[0];
    const int*   edge  = (const int*)d_in[1];   // [2][N_EDGES] int32
    const int*   batch = (const int*)d_in[2];   // [N_NODES] int32 (sorted)
    const float* W0  = (const float*)d_in[3];
    const float* b0  = (const float*)d_in[4];
    const float* W1a = (const float*)d_in[5];
    const float* b1a = (const float*)d_in[6];
    const float* W1b = (const float*)d_in[7];
    const float* b1b = (const float*)d_in[8];
    const float* W2a = (const float*)d_in[9];
    const float* b2a = (const float*)d_in[10];
    const float* W2b = (const float*)d_in[11];
    const float* b2b = (const float*)d_in[12];
    const float* W3a = (const float*)d_in[13];
    const float* b3a = (const float*)d_in[14];
    const float* W3b = (const float*)d_in[15];
    const float* b3b = (const float*)d_in[16];
    const float* Wl  = (const float*)d_in[17];
    const float* bl  = (const float*)d_in[18];
    float* out = (float*)d_out;

    const int* src = edge;
    const int* dst = edge + N_EDGES;

    // Workspace: HA(fp16) | Z(fp16) | cnt | rowptrL | buckets | WF(fp16)
    h16* HA = (h16*)d_ws;
    h16* Z  = HA + (size_t)N_NODES * HID;
    int* cnt     = (int*)(Z + (size_t)N_NODES * HID);
    int* rowptrL = cnt + NBUCKET * NREP;
    int* buckets = rowptrL + NBUCKET * 65;
    h16* WF      = (h16*)(buckets + (size_t)NBUCKET * BK_STRIDE);
    h16* W0F = WF;               // order: W0, W1a, W1b, W2a, W2b, W3a, W3b
    h16* W1aF = WF + 4096 * 1;
    h16* W1bF = WF + 4096 * 2;
    h16* W2aF = WF + 4096 * 3;
    h16* W2bF = WF + 4096 * 4;
    h16* W3aF = WF + 4096 * 5;
    h16* W3bF = WF + 4096 * 6;

    hipMemsetAsync(cnt, 0, NBUCKET * NREP * sizeof(int), stream);
    k_partition<<<(N_EDGES + 255) / 256, 256, 0, stream>>>(src, dst, cnt, buckets);
    k_bucket_sort<<<NBUCKET, 256, 0, stream>>>(cnt, buckets, rowptrL);
    k_wprep<<<7, 256, 0, stream>>>(W0, W1a, W1b, W2a, W2b, W3a, W3b, WF);

    k_lin<<<TILE1, 256, 0, stream>>>(W0F, b0, x, HA);

    k_aggregate<<<6250, 256, 0, stream>>>(rowptrL, buckets, HA, Z);
    k_mlp<<<TILE1, 256, 0, stream>>>(W1aF, b1a, W1bF, b1b, Z, HA);

    k_aggregate<<<6250, 256, 0, stream>>>(rowptrL, buckets, HA, Z);
    k_mlp<<<TILE1, 256, 0, stream>>>(W2aF, b2a, W2bF, b2b, Z, HA);

    k_aggregate<<<6250, 256, 0, stream>>>(rowptrL, buckets, HA, Z);
    k_mlp<<<TILE1, 256, 0, stream>>>(W3aF, b3a, W3bF, b3b, Z, HA);

    k_poolfinal<<<N_GRAPHS, 256, 0, stream>>>(HA, batch, Wl, bl, out);
}

// Round 15
// 295.465 us; speedup vs baseline: 1.4968x; 1.1192x over previous
//
#include <hip/hip_runtime.h>
#include <hip/hip_fp16.h>

#define N_NODES 100000
#define N_EDGES 1250000
#define HID 64
#define N_GRAPHS 512
#define OUT_CH 16

#define NSUP 196        // super-buckets of 512 nodes
#define SB_CAP 8192     // mean 6378, sigma ~80 -> +22σ
#define E_BLK 2048
#define NPB ((N_EDGES + E_BLK - 1) / E_BLK)  // 611
#define TILE1 ((N_NODES + 63) / 64)  // 1563 blocks
#define TSTRIDE 68      // LDS T row stride (floats)

typedef _Float16 h16;
typedef _Float16 half2_t __attribute__((ext_vector_type(2)));
typedef _Float16 f16x8 __attribute__((ext_vector_type(8)));
typedef float f32x4 __attribute__((ext_vector_type(4)));

__device__ __forceinline__ void acc4(uint2 u, float& a0, float& a1, float& a2, float& a3) {
    half2_t h0 = __builtin_bit_cast(half2_t, u.x);
    half2_t h1 = __builtin_bit_cast(half2_t, u.y);
    a0 += (float)h0[0];
    a1 += (float)h0[1];
    a2 += (float)h1[0];
    a3 += (float)h1[1];
}

__device__ __forceinline__ unsigned pack2(float x, float y) {
    half2_t o;
    o[0] = (h16)x;
    o[1] = (h16)y;
    return __builtin_bit_cast(unsigned, o);
}

// ===========================================================================
// Partition r15: 196 super-buckets (512 nodes). Block = 2048 edges:
// LDS hist -> block scan -> ONE global atomic per super per block (120K vs
// 1.25M) -> LDS stage sorted by super -> contiguous int4 run writes
// (~0.5M stores vs 1.25M scattered). Record = (d&511)<<17 | src.
// ===========================================================================
__global__ __launch_bounds__(256) void k_partition(const int* __restrict__ src,
                                                   const int* __restrict__ dst,
                                                   int* __restrict__ cnt,
                                                   int* __restrict__ buckets) {
    __shared__ int hist[256];    // counts -> local cursor
    __shared__ int gbase[256];
    __shared__ int tsum[256];
    __shared__ int stage[E_BLK];
    int t = threadIdx.x;
    int e0 = blockIdx.x * E_BLK;
    int eN = N_EDGES - e0;
    if (eN > E_BLK) eN = E_BLK;

    hist[t] = 0;
    __syncthreads();
    for (int i = t; i < eN; i += 256) atomicAdd(&hist[dst[e0 + i] >> 9], 1);
    __syncthreads();

    int c = hist[t];
    tsum[t] = c;
    __syncthreads();
    for (int off = 1; off < 256; off <<= 1) {
        int u = (t >= off) ? tsum[t - off] : 0;
        __syncthreads();
        tsum[t] += u;
        __syncthreads();
    }
    int pref = tsum[t] - c;
    if (t < NSUP && c > 0) gbase[t] = atomicAdd(&cnt[t], c);
    hist[t] = pref;  // becomes local cursor (all hist reads done pre-scan)
    __syncthreads();

    for (int i = t; i < eN; i += 256) {
        int s = src[e0 + i];
        int d = dst[e0 + i];
        int p = atomicAdd(&hist[d >> 9], 1);
        stage[p] = ((d & 511) << 17) | s;
    }
    __syncthreads();

    // write out: thread t owns super t; contiguous run, int4 where aligned
    if (t < NSUP && c > 0) {
        int lstart = hist[t] - c;
        int gb = gbase[t];
        int cap = SB_CAP - gb;
        int n = c < cap ? c : (cap > 0 ? cap : 0);
        int* dp = buckets + (size_t)t * SB_CAP + gb;
        int r = 0;
        while (r < n && (((size_t)(dp + r)) & 15)) { dp[r] = stage[lstart + r]; ++r; }
        for (; r + 4 <= n; r += 4) {
            int4 v;
            v.x = stage[lstart + r];
            v.y = stage[lstart + r + 1];
            v.z = stage[lstart + r + 2];
            v.w = stage[lstart + r + 3];
            *(int4*)(dp + r) = v;
        }
        for (; r < n; ++r) dp[r] = stage[lstart + r];
    }
}

// ===========================================================================
// Split r15: one block per super-bucket. Counting sort of ~6400 records by
// 9-bit dstLocal in LDS; coalesced read/write; emits rowptrS[s*513+l]
// (absolute indices into buckets[]).
// ===========================================================================
__global__ __launch_bounds__(256) void k_sort(const int* __restrict__ cnt,
                                              int* __restrict__ buckets,
                                              int* __restrict__ rowptrS) {
    __shared__ int srt[SB_CAP];   // 32 KB
    __shared__ int hist[512];
    __shared__ int curs[512];
    __shared__ int tsum[256];
    int s = blockIdx.x, t = threadIdx.x;
    int n = cnt[s];
    n = n < SB_CAP ? n : SB_CAP;
    int* gb = buckets + (size_t)s * SB_CAP;
    int sBase = s * SB_CAP;

    hist[t] = 0;
    hist[t + 256] = 0;
    __syncthreads();
    for (int i = t; i < n; i += 256) atomicAdd(&hist[gb[i] >> 17], 1);
    __syncthreads();

    int c0 = hist[2 * t], c1 = hist[2 * t + 1];
    int tot = c0 + c1;
    tsum[t] = tot;
    __syncthreads();
    for (int off = 1; off < 256; off <<= 1) {
        int u = (t >= off) ? tsum[t - off] : 0;
        __syncthreads();
        tsum[t] += u;
        __syncthreads();
    }
    int pref = tsum[t] - tot;
    curs[2 * t] = pref;
    curs[2 * t + 1] = pref + c0;
    rowptrS[s * 513 + 2 * t] = sBase + pref;
    rowptrS[s * 513 + 2 * t + 1] = sBase + pref + c0;
    if (t == 255) rowptrS[s * 513 + 512] = sBase + n;
    __syncthreads();

    for (int i = t; i < n; i += 256) {
        int rec = gb[i];
        int pos = atomicAdd(&curs[rec >> 17], 1);
        srt[pos] = rec;
    }
    __syncthreads();
    for (int i = t; i < n; i += 256) gb[i] = srt[i];
}

// ===========================================================================
// Aggregate (r14 quarter-wave + 8-deep, at its random-line floor): only the
// indexing changes (absolute rowptrS, global record indices).
// ===========================================================================
__global__ __launch_bounds__(256) void k_aggregate(const int* __restrict__ rowptrS,
                                                   const int* __restrict__ buckets,
                                                   const h16* __restrict__ H,
                                                   h16* __restrict__ Z) {
    const uint2* H4 = (const uint2*)H;  // 16 uint2 per row
    uint2* Z4 = (uint2*)Z;
    int lane = threadIdx.x & 63;
    int part = lane >> 4, sub = lane & 15;
    int gwave = (blockIdx.x * 256 + threadIdx.x) >> 6;
    int nw = (gridDim.x * 256) >> 6;
    for (int i0 = gwave * 4; i0 < N_NODES; i0 += nw * 4) {
        int i = i0 + part;
        bool valid = i < N_NODES;
        int iv = valid ? i : N_NODES - 1;
        int s = iv >> 9, l = iv & 511;
        int start = rowptrS[s * 513 + l];
        int end = valid ? rowptrS[s * 513 + l + 1] : start;
        float a0 = 0.f, a1 = 0.f, a2 = 0.f, a3 = 0.f;
        acc4(H4[(size_t)iv * 16 + sub], a0, a1, a2, a3);  // self term
        int j = start;
        for (; j + 8 <= end; j += 8) {
            int s0 = buckets[j] & 0x1FFFF;
            int s1 = buckets[j + 1] & 0x1FFFF;
            int s2 = buckets[j + 2] & 0x1FFFF;
            int s3 = buckets[j + 3] & 0x1FFFF;
            int s4 = buckets[j + 4] & 0x1FFFF;
            int s5 = buckets[j + 5] & 0x1FFFF;
            int s6 = buckets[j + 6] & 0x1FFFF;
            int s7 = buckets[j + 7] & 0x1FFFF;
            uint2 u0 = H4[(size_t)s0 * 16 + sub];
            uint2 u1 = H4[(size_t)s1 * 16 + sub];
            uint2 u2 = H4[(size_t)s2 * 16 + sub];
            uint2 u3 = H4[(size_t)s3 * 16 + sub];
            uint2 u4 = H4[(size_t)s4 * 16 + sub];
            uint2 u5 = H4[(size_t)s5 * 16 + sub];
            uint2 u6 = H4[(size_t)s6 * 16 + sub];
            uint2 u7 = H4[(size_t)s7 * 16 + sub];
            acc4(u0, a0, a1, a2, a3);
            acc4(u1, a0, a1, a2, a3);
            acc4(u2, a0, a1, a2, a3);
            acc4(u3, a0, a1, a2, a3);
            acc4(u4, a0, a1, a2, a3);
            acc4(u5, a0, a1, a2, a3);
            acc4(u6, a0, a1, a2, a3);
            acc4(u7, a0, a1, a2, a3);
        }
        if (j + 4 <= end) {
            int s0 = buckets[j] & 0x1FFFF;
            int s1 = buckets[j + 1] & 0x1FFFF;
            int s2 = buckets[j + 2] & 0x1FFFF;
            int s3 = buckets[j + 3] & 0x1FFFF;
            uint2 u0 = H4[(size_t)s0 * 16 + sub];
            uint2 u1 = H4[(size_t)s1 * 16 + sub];
            uint2 u2 = H4[(size_t)s2 * 16 + sub];
            uint2 u3 = H4[(size_t)s3 * 16 + sub];
            acc4(u0, a0, a1, a2, a3);
            acc4(u1, a0, a1, a2, a3);
            acc4(u2, a0, a1, a2, a3);
            acc4(u3, a0, a1, a2, a3);
            j += 4;
        }
        if (j + 2 <= end) {
            int s0 = buckets[j] & 0x1FFFF;
            int s1 = buckets[j + 1] & 0x1FFFF;
            uint2 u0 = H4[(size_t)s0 * 16 + sub];
            uint2 u1 = H4[(size_t)s1 * 16 + sub];
            acc4(u0, a0, a1, a2, a3);
            acc4(u1, a0, a1, a2, a3);
            j += 2;
        }
        if (j < end) {
            int s0 = buckets[j] & 0x1FFFF;
            acc4(H4[(size_t)s0 * 16 + sub], a0, a1, a2, a3);
        }
        if (valid) {
            uint2 o;
            o.x = pack2(a0, a1);
            o.y = pack2(a2, a3);
            Z4[(size_t)i * 16 + sub] = o;
        }
    }
}

// ===========================================================================
// Weight prep (once per call): swizzle 7 64x64 fp32 matrices into fp16
// B-fragment order for mfma_f32_16x16x32_f16. Unchanged.
// ===========================================================================
__global__ __launch_bounds__(256) void k_wprep(const float* __restrict__ Wq0,
                                               const float* __restrict__ Wq1,
                                               const float* __restrict__ Wq2,
                                               const float* __restrict__ Wq3,
                                               const float* __restrict__ Wq4,
                                               const float* __restrict__ Wq5,
                                               const float* __restrict__ Wq6,
                                               h16* __restrict__ WF) {
    const float* Ws[7] = {Wq0, Wq1, Wq2, Wq3, Wq4, Wq5, Wq6};
    const float* W = Ws[blockIdx.x];
    h16* dstW = WF + (size_t)blockIdx.x * 4096;
    int t = threadIdx.x;
#pragma unroll
    for (int i = 0; i < 16; ++i) {
        int s = t + 256 * i;
        int k = s >> 6, col = s & 63;
        int kc = k >> 5, quad = (k >> 3) & 3, j = k & 7;
        int c = col >> 4, n = col & 15;
        dstW[((c * 2 + kc) * 4 + quad) * 128 + n * 8 + j] = (h16)W[s];
    }
}

// ===========================================================================
// MFMA MLP (r10, proven). Unchanged.
// ===========================================================================
__global__ __launch_bounds__(256) void k_mlp(const h16* __restrict__ WaF,
                                             const float* __restrict__ Ba,
                                             const h16* __restrict__ WbF,
                                             const float* __restrict__ Bb,
                                             const h16* __restrict__ Zin,
                                             h16* __restrict__ Hout) {
    __shared__ float sT[4 * 16 * TSTRIDE];
    int t = threadIdx.x;
    int w = t >> 6, lane = t & 63;
    int n16 = lane & 15, quad = lane >> 4;
    float* T = sT + w * 16 * TSTRIDE;
    int rbase = blockIdx.x * 64 + w * 16;

    int arow = rbase + n16;
    int crow = arow < N_NODES ? arow : N_NODES - 1;
    const f16x8* zp = (const f16x8*)(Zin + (size_t)crow * HID + quad * 8);
    f16x8 a0 = zp[0];
    f16x8 a1 = zp[4];

    f16x8 bwa[4][2], bwb[4][2];
#pragma unroll
    for (int c = 0; c < 4; ++c)
#pragma unroll
        for (int kc = 0; kc < 2; ++kc) {
            int f = ((c * 2 + kc) * 4 + quad) * 128 + n16 * 8;
            bwa[c][kc] = *(const f16x8*)(WaF + f);
            bwb[c][kc] = *(const f16x8*)(WbF + f);
        }

    f32x4 acc[4];
#pragma unroll
    for (int c = 0; c < 4; ++c) {
        float bv = Ba[c * 16 + n16];
        acc[c] = (f32x4){bv, bv, bv, bv};
        acc[c] = __builtin_amdgcn_mfma_f32_16x16x32_f16(a0, bwa[c][0], acc[c], 0, 0, 0);
        acc[c] = __builtin_amdgcn_mfma_f32_16x16x32_f16(a1, bwa[c][1], acc[c], 0, 0, 0);
    }

#pragma unroll
    for (int c = 0; c < 4; ++c)
#pragma unroll
        for (int r = 0; r < 4; ++r)
            T[(quad * 4 + r) * TSTRIDE + c * 16 + n16] = fmaxf(acc[c][r], 0.f);

    f16x8 ta[2];
#pragma unroll
    for (int kc = 0; kc < 2; ++kc) {
        float4 p = *(const float4*)&T[n16 * TSTRIDE + kc * 32 + quad * 8];
        float4 q = *(const float4*)&T[n16 * TSTRIDE + kc * 32 + quad * 8 + 4];
        f16x8 v;
        v[0] = (h16)p.x; v[1] = (h16)p.y; v[2] = (h16)p.z; v[3] = (h16)p.w;
        v[4] = (h16)q.x; v[5] = (h16)q.y; v[6] = (h16)q.z; v[7] = (h16)q.w;
        ta[kc] = v;
    }

#pragma unroll
    for (int c = 0; c < 4; ++c) {
        float bv = Bb[c * 16 + n16];
        acc[c] = (f32x4){bv, bv, bv, bv};
        acc[c] = __builtin_amdgcn_mfma_f32_16x16x32_f16(ta[0], bwb[c][0], acc[c], 0, 0, 0);
        acc[c] = __builtin_amdgcn_mfma_f32_16x16x32_f16(ta[1], bwb[c][1], acc[c], 0, 0, 0);
    }

#pragma unroll
    for (int c = 0; c < 4; ++c)
#pragma unroll
        for (int r = 0; r < 4; ++r)
            T[(quad * 4 + r) * TSTRIDE + c * 16 + n16] = fmaxf(acc[c][r], 0.f);
    {
        int rl = lane >> 2, seg = lane & 3;
        int row = rbase + rl;
        if (row < N_NODES) {
            const float* tr = &T[rl * TSTRIDE + seg * 16];
            f16x8 o0, o1;
#pragma unroll
            for (int i = 0; i < 8; ++i) {
                o0[i] = (h16)tr[i];
                o1[i] = (h16)tr[8 + i];
            }
            f16x8* dp = (f16x8*)(Hout + (size_t)row * HID + seg * 16);
            dp[0] = o0;
            dp[1] = o1;
        }
    }
}

// ===========================================================================
// MFMA input linear (r10, proven). Unchanged.
// ===========================================================================
__global__ __launch_bounds__(256) void k_lin(const h16* __restrict__ W0F,
                                             const float* __restrict__ B,
                                             const float* __restrict__ Xin,
                                             h16* __restrict__ Hout) {
    __shared__ float sT[4 * 16 * TSTRIDE];
    int t = threadIdx.x;
    int w = t >> 6, lane = t & 63;
    int n16 = lane & 15, quad = lane >> 4;
    float* T = sT + w * 16 * TSTRIDE;
    int rbase = blockIdx.x * 64 + w * 16;

    int arow = rbase + n16;
    int crow = arow < N_NODES ? arow : N_NODES - 1;
    f16x8 a[2];
#pragma unroll
    for (int kc = 0; kc < 2; ++kc) {
        const float4* xp = (const float4*)(Xin + (size_t)crow * HID + kc * 32 + quad * 8);
        float4 p = xp[0], q = xp[1];
        f16x8 v;
        v[0] = (h16)p.x; v[1] = (h16)p.y; v[2] = (h16)p.z; v[3] = (h16)p.w;
        v[4] = (h16)q.x; v[5] = (h16)q.y; v[6] = (h16)q.z; v[7] = (h16)q.w;
        a[kc] = v;
    }

    f32x4 acc[4];
#pragma unroll
    for (int c = 0; c < 4; ++c) {
        float bv = B[c * 16 + n16];
        acc[c] = (f32x4){bv, bv, bv, bv};
#pragma unroll
        for (int kc = 0; kc < 2; ++kc) {
            f16x8 bw = *(const f16x8*)(W0F + ((c * 2 + kc) * 4 + quad) * 128 + n16 * 8);
            acc[c] = __builtin_amdgcn_mfma_f32_16x16x32_f16(a[kc], bw, acc[c], 0, 0, 0);
        }
    }

#pragma unroll
    for (int c = 0; c < 4; ++c)
#pragma unroll
        for (int r = 0; r < 4; ++r)
            T[(quad * 4 + r) * TSTRIDE + c * 16 + n16] = fmaxf(acc[c][r], 0.f);
    {
        int rl = lane >> 2, seg = lane & 3;
        int row = rbase + rl;
        if (row < N_NODES) {
            const float* tr = &T[rl * TSTRIDE + seg * 16];
            f16x8 o0, o1;
#pragma unroll
            for (int i = 0; i < 8; ++i) {
                o0[i] = (h16)tr[i];
                o1[i] = (h16)tr[8 + i];
            }
            f16x8* dp = (f16x8*)(Hout + (size_t)row * HID + seg * 16);
            dp[0] = o0;
            dp[1] = o1;
        }
    }
}

// ===========================================================================
// Fused mean-pool + readout: one block per graph. Unchanged.
// ===========================================================================
__global__ __launch_bounds__(256) void k_poolfinal(const h16* __restrict__ H,
                                                   const int* __restrict__ batch,
                                                   const float* __restrict__ Wl,
                                                   const float* __restrict__ bl,
                                                   float* __restrict__ out) {
    __shared__ float sp[4 * HID];
    int g = blockIdx.x;
    int t = threadIdx.x;
    int lane = t & 63, w = t >> 6;
    int lo = 0, hi = N_NODES;
    while (lo < hi) { int m = (lo + hi) >> 1; if (batch[m] < g) lo = m + 1; else hi = m; }
    int start = lo;
    hi = N_NODES;
    while (lo < hi) { int m = (lo + hi) >> 1; if (batch[m] < g + 1) lo = m + 1; else hi = m; }
    int end = lo;
    float s = 0.f;
    for (int r = start + w; r < end; r += 4) s += (float)H[(size_t)r * HID + lane];
    sp[w * HID + lane] = s;
    __syncthreads();
    if (t < HID) {
        float tot = sp[t] + sp[HID + t] + sp[2 * HID + t] + sp[3 * HID + t];
        float c = (end > start) ? (float)(end - start) : 1.0f;
        sp[t] = tot / c;
    }
    __syncthreads();
    if (t < OUT_CH) {
        float acc = bl[t];
#pragma unroll
        for (int k = 0; k < HID; ++k) acc += sp[k] * Wl[k * OUT_CH + t];
        out[g * OUT_CH + t] = acc;
    }
}

extern "C" void kernel_launch(void* const* d_in, const int* in_sizes, int n_in,
                              void* d_out, int out_size, void* d_ws, size_t ws_size,
                              hipStream_t stream) {
    const float* x     = (const float*)d_in[0];
    const int*   edge  = (const int*)d_in[1];   // [2][N_EDGES] int32
    const int*   batch = (const int*)d_in[2];   // [N_NODES] int32 (sorted)
    const float* W0  = (const float*)d_in[3];
    const float* b0  = (const float*)d_in[4];
    const float* W1a = (const float*)d_in[5];
    const float* b1a = (const float*)d_in[6];
    const float* W1b = (const float*)d_in[7];
    const float* b1b = (const float*)d_in[8];
    const float* W2a = (const float*)d_in[9];
    const float* b2a = (const float*)d_in[10];
    const float* W2b = (const float*)d_in[11];
    const float* b2b = (const float*)d_in[12];
    const float* W3a = (const float*)d_in[13];
    const float* b3a = (const float*)d_in[14];
    const float* W3b = (const float*)d_in[15];
    const float* b3b = (const float*)d_in[16];
    const float* Wl  = (const float*)d_in[17];
    const float* bl  = (const float*)d_in[18];
    float* out = (float*)d_out;

    const int* src = edge;
    const int* dst = edge + N_EDGES;

    // Workspace: HA(fp16) | Z(fp16) | cnt | rowptrS | buckets | WF(fp16)
    h16* HA = (h16*)d_ws;
    h16* Z  = HA + (size_t)N_NODES * HID;
    int* cnt     = (int*)(Z + (size_t)N_NODES * HID);
    int* rowptrS = cnt + NSUP;
    int* buckets = rowptrS + NSUP * 513;
    h16* WF      = (h16*)(buckets + (size_t)NSUP * SB_CAP);
    h16* W0F = WF;               // order: W0, W1a, W1b, W2a, W2b, W3a, W3b
    h16* W1aF = WF + 4096 * 1;
    h16* W1bF = WF + 4096 * 2;
    h16* W2aF = WF + 4096 * 3;
    h16* W2bF = WF + 4096 * 4;
    h16* W3aF = WF + 4096 * 5;
    h16* W3bF = WF + 4096 * 6;

    hipMemsetAsync(cnt, 0, NSUP * sizeof(int), stream);
    k_partition<<<NPB, 256, 0, stream>>>(src, dst, cnt, buckets);
    k_sort<<<NSUP, 256, 0, stream>>>(cnt, buckets, rowptrS);
    k_wprep<<<7, 256, 0, stream>>>(W0, W1a, W1b, W2a, W2b, W3a, W3b, WF);

    k_lin<<<TILE1, 256, 0, stream>>>(W0F, b0, x, HA);

    k_aggregate<<<6250, 256, 0, stream>>>(rowptrS, buckets, HA, Z);
    k_mlp<<<TILE1, 256, 0, stream>>>(W1aF, b1a, W1bF, b1b, Z, HA);

    k_aggregate<<<6250, 256, 0, stream>>>(rowptrS, buckets, HA, Z);
    k_mlp<<<TILE1, 256, 0, stream>>>(W2aF, b2a, W2bF, b2b, Z, HA);

    k_aggregate<<<6250, 256, 0, stream>>>(rowptrS, buckets, HA, Z);
    k_mlp<<<TILE1, 256, 0, stream>>>(W3aF, b3a, W3bF, b3b, Z, HA);

    k_poolfinal<<<N_GRAPHS, 256, 0, stream>>>(HA, batch, Wl, bl, out);
}

// Round 16
// 286.125 us; speedup vs baseline: 1.5456x; 1.0326x over previous
//
#include <hip/hip_runtime.h>
#include <hip/hip_fp16.h>

#define N_NODES 100000
#define N_EDGES 1250000
#define HID 64
#define N_GRAPHS 512
#define OUT_CH 16

#define NSUP 196        // super-buckets of 512 nodes
#define SB_CAP 8192     // mean 6378, sigma ~80 -> +22σ
#define E_BLK 2048
#define NPB ((N_EDGES + E_BLK - 1) / E_BLK)  // 611
#define TILE2 ((N_NODES + 127) / 128)  // 782 blocks (2 row-tiles each)
#define TSTRIDE 68      // LDS T row stride (floats)

typedef _Float16 h16;
typedef _Float16 half2_t __attribute__((ext_vector_type(2)));
typedef _Float16 f16x8 __attribute__((ext_vector_type(8)));
typedef float f32x4 __attribute__((ext_vector_type(4)));

__device__ __forceinline__ void acc4(uint2 u, float& a0, float& a1, float& a2, float& a3) {
    half2_t h0 = __builtin_bit_cast(half2_t, u.x);
    half2_t h1 = __builtin_bit_cast(half2_t, u.y);
    a0 += (float)h0[0];
    a1 += (float)h0[1];
    a2 += (float)h1[0];
    a3 += (float)h1[1];
}

__device__ __forceinline__ unsigned pack2(float x, float y) {
    half2_t o;
    o[0] = (h16)x;
    o[1] = (h16)y;
    return __builtin_bit_cast(unsigned, o);
}

// ===========================================================================
// Partition r15 (proven): 196 super-buckets; LDS hist -> 1 atomic/super/blk
// -> LDS stage -> contiguous int4 run writes. Record = (d&511)<<17 | src.
// ===========================================================================
__global__ __launch_bounds__(256) void k_partition(const int* __restrict__ src,
                                                   const int* __restrict__ dst,
                                                   int* __restrict__ cnt,
                                                   int* __restrict__ buckets) {
    __shared__ int hist[256];
    __shared__ int gbase[256];
    __shared__ int tsum[256];
    __shared__ int stage[E_BLK];
    int t = threadIdx.x;
    int e0 = blockIdx.x * E_BLK;
    int eN = N_EDGES - e0;
    if (eN > E_BLK) eN = E_BLK;

    hist[t] = 0;
    __syncthreads();
    for (int i = t; i < eN; i += 256) atomicAdd(&hist[dst[e0 + i] >> 9], 1);
    __syncthreads();

    int c = hist[t];
    tsum[t] = c;
    __syncthreads();
    for (int off = 1; off < 256; off <<= 1) {
        int u = (t >= off) ? tsum[t - off] : 0;
        __syncthreads();
        tsum[t] += u;
        __syncthreads();
    }
    int pref = tsum[t] - c;
    if (t < NSUP && c > 0) gbase[t] = atomicAdd(&cnt[t], c);
    hist[t] = pref;
    __syncthreads();

    for (int i = t; i < eN; i += 256) {
        int s = src[e0 + i];
        int d = dst[e0 + i];
        int p = atomicAdd(&hist[d >> 9], 1);
        stage[p] = ((d & 511) << 17) | s;
    }
    __syncthreads();

    if (t < NSUP && c > 0) {
        int lstart = hist[t] - c;
        int gb = gbase[t];
        int cap = SB_CAP - gb;
        int n = c < cap ? c : (cap > 0 ? cap : 0);
        int* dp = buckets + (size_t)t * SB_CAP + gb;
        int r = 0;
        while (r < n && (((size_t)(dp + r)) & 15)) { dp[r] = stage[lstart + r]; ++r; }
        for (; r + 4 <= n; r += 4) {
            int4 v;
            v.x = stage[lstart + r];
            v.y = stage[lstart + r + 1];
            v.z = stage[lstart + r + 2];
            v.w = stage[lstart + r + 3];
            *(int4*)(dp + r) = v;
        }
        for (; r < n; ++r) dp[r] = stage[lstart + r];
    }
}

// ===========================================================================
// Split r15 (proven): counting sort per super by 9-bit dstLocal; emits
// absolute rowptrS[s*513+l].
// ===========================================================================
__global__ __launch_bounds__(256) void k_sort(const int* __restrict__ cnt,
                                              int* __restrict__ buckets,
                                              int* __restrict__ rowptrS) {
    __shared__ int srt[SB_CAP];   // 32 KB
    __shared__ int hist[512];
    __shared__ int curs[512];
    __shared__ int tsum[256];
    int s = blockIdx.x, t = threadIdx.x;
    int n = cnt[s];
    n = n < SB_CAP ? n : SB_CAP;
    int* gb = buckets + (size_t)s * SB_CAP;
    int sBase = s * SB_CAP;

    hist[t] = 0;
    hist[t + 256] = 0;
    __syncthreads();
    for (int i = t; i < n; i += 256) atomicAdd(&hist[gb[i] >> 17], 1);
    __syncthreads();

    int c0 = hist[2 * t], c1 = hist[2 * t + 1];
    int tot = c0 + c1;
    tsum[t] = tot;
    __syncthreads();
    for (int off = 1; off < 256; off <<= 1) {
        int u = (t >= off) ? tsum[t - off] : 0;
        __syncthreads();
        tsum[t] += u;
        __syncthreads();
    }
    int pref = tsum[t] - tot;
    curs[2 * t] = pref;
    curs[2 * t + 1] = pref + c0;
    rowptrS[s * 513 + 2 * t] = sBase + pref;
    rowptrS[s * 513 + 2 * t + 1] = sBase + pref + c0;
    if (t == 255) rowptrS[s * 513 + 512] = sBase + n;
    __syncthreads();

    for (int i = t; i < n; i += 256) {
        int rec = gb[i];
        int pos = atomicAdd(&curs[rec >> 17], 1);
        srt[pos] = rec;
    }
    __syncthreads();
    for (int i = t; i < n; i += 256) gb[i] = srt[i];
}

// ===========================================================================
// Aggregate (r14/r15, at its random-line floor). Unchanged.
// ===========================================================================
__global__ __launch_bounds__(256) void k_aggregate(const int* __restrict__ rowptrS,
                                                   const int* __restrict__ buckets,
                                                   const h16* __restrict__ H,
                                                   h16* __restrict__ Z) {
    const uint2* H4 = (const uint2*)H;
    uint2* Z4 = (uint2*)Z;
    int lane = threadIdx.x & 63;
    int part = lane >> 4, sub = lane & 15;
    int gwave = (blockIdx.x * 256 + threadIdx.x) >> 6;
    int nw = (gridDim.x * 256) >> 6;
    for (int i0 = gwave * 4; i0 < N_NODES; i0 += nw * 4) {
        int i = i0 + part;
        bool valid = i < N_NODES;
        int iv = valid ? i : N_NODES - 1;
        int s = iv >> 9, l = iv & 511;
        int start = rowptrS[s * 513 + l];
        int end = valid ? rowptrS[s * 513 + l + 1] : start;
        float a0 = 0.f, a1 = 0.f, a2 = 0.f, a3 = 0.f;
        acc4(H4[(size_t)iv * 16 + sub], a0, a1, a2, a3);
        int j = start;
        for (; j + 8 <= end; j += 8) {
            int s0 = buckets[j] & 0x1FFFF;
            int s1 = buckets[j + 1] & 0x1FFFF;
            int s2 = buckets[j + 2] & 0x1FFFF;
            int s3 = buckets[j + 3] & 0x1FFFF;
            int s4 = buckets[j + 4] & 0x1FFFF;
            int s5 = buckets[j + 5] & 0x1FFFF;
            int s6 = buckets[j + 6] & 0x1FFFF;
            int s7 = buckets[j + 7] & 0x1FFFF;
            uint2 u0 = H4[(size_t)s0 * 16 + sub];
            uint2 u1 = H4[(size_t)s1 * 16 + sub];
            uint2 u2 = H4[(size_t)s2 * 16 + sub];
            uint2 u3 = H4[(size_t)s3 * 16 + sub];
            uint2 u4 = H4[(size_t)s4 * 16 + sub];
            uint2 u5 = H4[(size_t)s5 * 16 + sub];
            uint2 u6 = H4[(size_t)s6 * 16 + sub];
            uint2 u7 = H4[(size_t)s7 * 16 + sub];
            acc4(u0, a0, a1, a2, a3);
            acc4(u1, a0, a1, a2, a3);
            acc4(u2, a0, a1, a2, a3);
            acc4(u3, a0, a1, a2, a3);
            acc4(u4, a0, a1, a2, a3);
            acc4(u5, a0, a1, a2, a3);
            acc4(u6, a0, a1, a2, a3);
            acc4(u7, a0, a1, a2, a3);
        }
        if (j + 4 <= end) {
            int s0 = buckets[j] & 0x1FFFF;
            int s1 = buckets[j + 1] & 0x1FFFF;
            int s2 = buckets[j + 2] & 0x1FFFF;
            int s3 = buckets[j + 3] & 0x1FFFF;
            uint2 u0 = H4[(size_t)s0 * 16 + sub];
            uint2 u1 = H4[(size_t)s1 * 16 + sub];
            uint2 u2 = H4[(size_t)s2 * 16 + sub];
            uint2 u3 = H4[(size_t)s3 * 16 + sub];
            acc4(u0, a0, a1, a2, a3);
            acc4(u1, a0, a1, a2, a3);
            acc4(u2, a0, a1, a2, a3);
            acc4(u3, a0, a1, a2, a3);
            j += 4;
        }
        if (j + 2 <= end) {
            int s0 = buckets[j] & 0x1FFFF;
            int s1 = buckets[j + 1] & 0x1FFFF;
            uint2 u0 = H4[(size_t)s0 * 16 + sub];
            uint2 u1 = H4[(size_t)s1 * 16 + sub];
            acc4(u0, a0, a1, a2, a3);
            acc4(u1, a0, a1, a2, a3);
            j += 2;
        }
        if (j < end) {
            int s0 = buckets[j] & 0x1FFFF;
            acc4(H4[(size_t)s0 * 16 + sub], a0, a1, a2, a3);
        }
        if (valid) {
            uint2 o;
            o.x = pack2(a0, a1);
            o.y = pack2(a2, a3);
            Z4[(size_t)i * 16 + sub] = o;
        }
    }
}

// ===========================================================================
// Weight prep (once per call). Unchanged.
// ===========================================================================
__global__ __launch_bounds__(256) void k_wprep(const float* __restrict__ Wq0,
                                               const float* __restrict__ Wq1,
                                               const float* __restrict__ Wq2,
                                               const float* __restrict__ Wq3,
                                               const float* __restrict__ Wq4,
                                               const float* __restrict__ Wq5,
                                               const float* __restrict__ Wq6,
                                               h16* __restrict__ WF) {
    const float* Ws[7] = {Wq0, Wq1, Wq2, Wq3, Wq4, Wq5, Wq6};
    const float* W = Ws[blockIdx.x];
    h16* dstW = WF + (size_t)blockIdx.x * 4096;
    int t = threadIdx.x;
#pragma unroll
    for (int i = 0; i < 16; ++i) {
        int s = t + 256 * i;
        int k = s >> 6, col = s & 63;
        int kc = k >> 5, quad = (k >> 3) & 3, j = k & 7;
        int c = col >> 4, n = col & 15;
        dstW[((c * 2 + kc) * 4 + quad) * 128 + n * 8 + j] = (h16)W[s];
    }
}

// ===========================================================================
// MFMA MLP r16: 2 row-tiles (128 rows) per block. B-frags (16 KB weights/
// wave) loaded ONCE and reused across both tiles -> halves weight traffic
// and block count. Wave-private, zero __syncthreads (r10 core).
// ===========================================================================
__global__ __launch_bounds__(256) void k_mlp(const h16* __restrict__ WaF,
                                             const float* __restrict__ Ba,
                                             const h16* __restrict__ WbF,
                                             const float* __restrict__ Bb,
                                             const h16* __restrict__ Zin,
                                             h16* __restrict__ Hout) {
    __shared__ float sT[4 * 16 * TSTRIDE];
    int t = threadIdx.x;
    int w = t >> 6, lane = t & 63;
    int n16 = lane & 15, quad = lane >> 4;
    float* T = sT + w * 16 * TSTRIDE;

    f16x8 bwa[4][2], bwb[4][2];
#pragma unroll
    for (int c = 0; c < 4; ++c)
#pragma unroll
        for (int kc = 0; kc < 2; ++kc) {
            int f = ((c * 2 + kc) * 4 + quad) * 128 + n16 * 8;
            bwa[c][kc] = *(const f16x8*)(WaF + f);
            bwb[c][kc] = *(const f16x8*)(WbF + f);
        }
    float bva[4], bvb[4];
#pragma unroll
    for (int c = 0; c < 4; ++c) {
        bva[c] = Ba[c * 16 + n16];
        bvb[c] = Bb[c * 16 + n16];
    }

#pragma unroll
    for (int tt = 0; tt < 2; ++tt) {
        int rbase = blockIdx.x * 128 + tt * 64 + w * 16;
        int arow = rbase + n16;
        int crow = arow < N_NODES ? arow : N_NODES - 1;
        const f16x8* zp = (const f16x8*)(Zin + (size_t)crow * HID + quad * 8);
        f16x8 a0 = zp[0];
        f16x8 a1 = zp[4];

        f32x4 acc[4];
#pragma unroll
        for (int c = 0; c < 4; ++c) {
            acc[c] = (f32x4){bva[c], bva[c], bva[c], bva[c]};
            acc[c] = __builtin_amdgcn_mfma_f32_16x16x32_f16(a0, bwa[c][0], acc[c], 0, 0, 0);
            acc[c] = __builtin_amdgcn_mfma_f32_16x16x32_f16(a1, bwa[c][1], acc[c], 0, 0, 0);
        }

#pragma unroll
        for (int c = 0; c < 4; ++c)
#pragma unroll
            for (int r = 0; r < 4; ++r)
                T[(quad * 4 + r) * TSTRIDE + c * 16 + n16] = fmaxf(acc[c][r], 0.f);

        f16x8 ta[2];
#pragma unroll
        for (int kc = 0; kc < 2; ++kc) {
            float4 p = *(const float4*)&T[n16 * TSTRIDE + kc * 32 + quad * 8];
            float4 q = *(const float4*)&T[n16 * TSTRIDE + kc * 32 + quad * 8 + 4];
            f16x8 v;
            v[0] = (h16)p.x; v[1] = (h16)p.y; v[2] = (h16)p.z; v[3] = (h16)p.w;
            v[4] = (h16)q.x; v[5] = (h16)q.y; v[6] = (h16)q.z; v[7] = (h16)q.w;
            ta[kc] = v;
        }

#pragma unroll
        for (int c = 0; c < 4; ++c) {
            acc[c] = (f32x4){bvb[c], bvb[c], bvb[c], bvb[c]};
            acc[c] = __builtin_amdgcn_mfma_f32_16x16x32_f16(ta[0], bwb[c][0], acc[c], 0, 0, 0);
            acc[c] = __builtin_amdgcn_mfma_f32_16x16x32_f16(ta[1], bwb[c][1], acc[c], 0, 0, 0);
        }

#pragma unroll
        for (int c = 0; c < 4; ++c)
#pragma unroll
            for (int r = 0; r < 4; ++r)
                T[(quad * 4 + r) * TSTRIDE + c * 16 + n16] = fmaxf(acc[c][r], 0.f);
        {
            int rl = lane >> 2, seg = lane & 3;
            int row = rbase + rl;
            if (row < N_NODES) {
                const float* tr = &T[rl * TSTRIDE + seg * 16];
                f16x8 o0, o1;
#pragma unroll
                for (int i = 0; i < 8; ++i) {
                    o0[i] = (h16)tr[i];
                    o1[i] = (h16)tr[8 + i];
                }
                f16x8* dp = (f16x8*)(Hout + (size_t)row * HID + seg * 16);
                dp[0] = o0;
                dp[1] = o1;
            }
        }
    }
}

// ===========================================================================
// MFMA input linear r16: 2 row-tiles per block (same reuse lever).
// ===========================================================================
__global__ __launch_bounds__(256) void k_lin(const h16* __restrict__ W0F,
                                             const float* __restrict__ B,
                                             const float* __restrict__ Xin,
                                             h16* __restrict__ Hout) {
    __shared__ float sT[4 * 16 * TSTRIDE];
    int t = threadIdx.x;
    int w = t >> 6, lane = t & 63;
    int n16 = lane & 15, quad = lane >> 4;
    float* T = sT + w * 16 * TSTRIDE;

    f16x8 bw[4][2];
#pragma unroll
    for (int c = 0; c < 4; ++c)
#pragma unroll
        for (int kc = 0; kc < 2; ++kc)
            bw[c][kc] = *(const f16x8*)(W0F + ((c * 2 + kc) * 4 + quad) * 128 + n16 * 8);
    float bv[4];
#pragma unroll
    for (int c = 0; c < 4; ++c) bv[c] = B[c * 16 + n16];

#pragma unroll
    for (int tt = 0; tt < 2; ++tt) {
        int rbase = blockIdx.x * 128 + tt * 64 + w * 16;
        int arow = rbase + n16;
        int crow = arow < N_NODES ? arow : N_NODES - 1;
        f16x8 a[2];
#pragma unroll
        for (int kc = 0; kc < 2; ++kc) {
            const float4* xp = (const float4*)(Xin + (size_t)crow * HID + kc * 32 + quad * 8);
            float4 p = xp[0], q = xp[1];
            f16x8 v;
            v[0] = (h16)p.x; v[1] = (h16)p.y; v[2] = (h16)p.z; v[3] = (h16)p.w;
            v[4] = (h16)q.x; v[5] = (h16)q.y; v[6] = (h16)q.z; v[7] = (h16)q.w;
            a[kc] = v;
        }

        f32x4 acc[4];
#pragma unroll
        for (int c = 0; c < 4; ++c) {
            acc[c] = (f32x4){bv[c], bv[c], bv[c], bv[c]};
#pragma unroll
            for (int kc = 0; kc < 2; ++kc)
                acc[c] = __builtin_amdgcn_mfma_f32_16x16x32_f16(a[kc], bw[c][kc], acc[c], 0, 0, 0);
        }

#pragma unroll
        for (int c = 0; c < 4; ++c)
#pragma unroll
            for (int r = 0; r < 4; ++r)
                T[(quad * 4 + r) * TSTRIDE + c * 16 + n16] = fmaxf(acc[c][r], 0.f);
        {
            int rl = lane >> 2, seg = lane & 3;
            int row = rbase + rl;
            if (row < N_NODES) {
                const float* tr = &T[rl * TSTRIDE + seg * 16];
                f16x8 o0, o1;
#pragma unroll
                for (int i = 0; i < 8; ++i) {
                    o0[i] = (h16)tr[i];
                    o1[i] = (h16)tr[8 + i];
                }
                f16x8* dp = (f16x8*)(Hout + (size_t)row * HID + seg * 16);
                dp[0] = o0;
                dp[1] = o1;
            }
        }
    }
}

// ===========================================================================
// Fused mean-pool + readout r16: 4-deep unrolled row loop (independent
// accumulators -> 4 loads in flight per lane; r11/r14 lever).
// ===========================================================================
__global__ __launch_bounds__(256) void k_poolfinal(const h16* __restrict__ H,
                                                   const int* __restrict__ batch,
                                                   const float* __restrict__ Wl,
                                                   const float* __restrict__ bl,
                                                   float* __restrict__ out) {
    __shared__ float sp[4 * HID];
    int g = blockIdx.x;
    int t = threadIdx.x;
    int lane = t & 63, w = t >> 6;
    int lo = 0, hi = N_NODES;
    while (lo < hi) { int m = (lo + hi) >> 1; if (batch[m] < g) lo = m + 1; else hi = m; }
    int start = lo;
    hi = N_NODES;
    while (lo < hi) { int m = (lo + hi) >> 1; if (batch[m] < g + 1) lo = m + 1; else hi = m; }
    int end = lo;
    float s0 = 0.f, s1 = 0.f, s2 = 0.f, s3 = 0.f;
    int r = start + w;
    for (; r + 12 < end; r += 16) {
        float v0 = (float)H[(size_t)r * HID + lane];
        float v1 = (float)H[(size_t)(r + 4) * HID + lane];
        float v2 = (float)H[(size_t)(r + 8) * HID + lane];
        float v3 = (float)H[(size_t)(r + 12) * HID + lane];
        s0 += v0; s1 += v1; s2 += v2; s3 += v3;
    }
    for (; r < end; r += 4) s0 += (float)H[(size_t)r * HID + lane];
    sp[w * HID + lane] = s0 + s1 + s2 + s3;
    __syncthreads();
    if (t < HID) {
        float tot = sp[t] + sp[HID + t] + sp[2 * HID + t] + sp[3 * HID + t];
        float c = (end > start) ? (float)(end - start) : 1.0f;
        sp[t] = tot / c;
    }
    __syncthreads();
    if (t < OUT_CH) {
        float acc = bl[t];
#pragma unroll
        for (int k = 0; k < HID; ++k) acc += sp[k] * Wl[k * OUT_CH + t];
        out[g * OUT_CH + t] = acc;
    }
}

extern "C" void kernel_launch(void* const* d_in, const int* in_sizes, int n_in,
                              void* d_out, int out_size, void* d_ws, size_t ws_size,
                              hipStream_t stream) {
    const float* x     = (const float*)d_in[0];
    const int*   edge  = (const int*)d_in[1];   // [2][N_EDGES] int32
    const int*   batch = (const int*)d_in[2];   // [N_NODES] int32 (sorted)
    const float* W0  = (const float*)d_in[3];
    const float* b0  = (const float*)d_in[4];
    const float* W1a = (const float*)d_in[5];
    const float* b1a = (const float*)d_in[6];
    const float* W1b = (const float*)d_in[7];
    const float* b1b = (const float*)d_in[8];
    const float* W2a = (const float*)d_in[9];
    const float* b2a = (const float*)d_in[10];
    const float* W2b = (const float*)d_in[11];
    const float* b2b = (const float*)d_in[12];
    const float* W3a = (const float*)d_in[13];
    const float* b3a = (const float*)d_in[14];
    const float* W3b = (const float*)d_in[15];
    const float* b3b = (const float*)d_in[16];
    const float* Wl  = (const float*)d_in[17];
    const float* bl  = (const float*)d_in[18];
    float* out = (float*)d_out;

    const int* src = edge;
    const int* dst = edge + N_EDGES;

    // Workspace: HA(fp16) | Z(fp16) | cnt | rowptrS | buckets | WF(fp16)
    h16* HA = (h16*)d_ws;
    h16* Z  = HA + (size_t)N_NODES * HID;
    int* cnt     = (int*)(Z + (size_t)N_NODES * HID);
    int* rowptrS = cnt + NSUP;
    int* buckets = rowptrS + NSUP * 513;
    h16* WF      = (h16*)(buckets + (size_t)NSUP * SB_CAP);
    h16* W0F = WF;               // order: W0, W1a, W1b, W2a, W2b, W3a, W3b
    h16* W1aF = WF + 4096 * 1;
    h16* W1bF = WF + 4096 * 2;
    h16* W2aF = WF + 4096 * 3;
    h16* W2bF = WF + 4096 * 4;
    h16* W3aF = WF + 4096 * 5;
    h16* W3bF = WF + 4096 * 6;

    hipMemsetAsync(cnt, 0, NSUP * sizeof(int), stream);
    k_partition<<<NPB, 256, 0, stream>>>(src, dst, cnt, buckets);
    k_sort<<<NSUP, 256, 0, stream>>>(cnt, buckets, rowptrS);
    k_wprep<<<7, 256, 0, stream>>>(W0, W1a, W1b, W2a, W2b, W3a, W3b, WF);

    k_lin<<<TILE2, 256, 0, stream>>>(W0F, b0, x, HA);

    k_aggregate<<<6250, 256, 0, stream>>>(rowptrS, buckets, HA, Z);
    k_mlp<<<TILE2, 256, 0, stream>>>(W1aF, b1a, W1bF, b1b, Z, HA);

    k_aggregate<<<6250, 256, 0, stream>>>(rowptrS, buckets, HA, Z);
    k_mlp<<<TILE2, 256, 0, stream>>>(W2aF, b2a, W2bF, b2b, Z, HA);

    k_aggregate<<<6250, 256, 0, stream>>>(rowptrS, buckets, HA, Z);
    k_mlp<<<TILE2, 256, 0, stream>>>(W3aF, b3a, W3bF, b3b, Z, HA);

    k_poolfinal<<<N_GRAPHS, 256, 0, stream>>>(HA, batch, Wl, bl, out);
}